// Round 1
// 1428.234 us; speedup vs baseline: 1.1302x; 1.1302x over previous
//
#include <hip/hip_runtime.h>

#define NTOK   4096   // BATCH * L
#define LSEQ   2048
#define DMODEL 2048
#define DINNER 4096
#define NSTATE 16
#define NCHAIN 8192   // BATCH * DINNER

using short8 = __attribute__((ext_vector_type(8))) short;
using f32x4  = __attribute__((ext_vector_type(4))) float;

__device__ inline float b2f(short s) {
    union { unsigned u; float f; } v;
    v.u = ((unsigned)(unsigned short)s) << 16;
    return v.f;
}
__device__ inline short f2b(float f) {
    unsigned u = __float_as_uint(f);
    unsigned r = (u + 0x7fffu + ((u >> 16) & 1u)) >> 16;
    return (short)r;
}

// ---------------------------------------------------------------------------
// fp32 -> bf16 bulk convert (8 elems/thread)
// ---------------------------------------------------------------------------
__global__ __launch_bounds__(256) void f32_to_bf16_kernel(
    const float* __restrict__ in, short* __restrict__ out, int n8) {
    int i = blockIdx.x * 256 + threadIdx.x;
    if (i >= n8) return;
    const float4* p = (const float4*)in + 2 * (size_t)i;
    float4 a = p[0], b = p[1];
    short8 s;
    s[0] = f2b(a.x); s[1] = f2b(a.y); s[2] = f2b(a.z); s[3] = f2b(a.w);
    s[4] = f2b(b.x); s[5] = f2b(b.y); s[6] = f2b(b.z); s[7] = f2b(b.w);
    *(short8*)(out + 8 * (size_t)i) = s;
}

// ---------------------------------------------------------------------------
// RMSNorm: x (NTOK x DMODEL fp32) -> xn bf16
// ---------------------------------------------------------------------------
__global__ __launch_bounds__(256) void rmsnorm_kernel(
    const float* __restrict__ x, const float* __restrict__ w,
    short* __restrict__ xn) {
    const int t = blockIdx.x, tid = threadIdx.x;
    const float4* xr = (const float4*)(x + (size_t)t * DMODEL + tid * 8);
    float4 a = xr[0], b = xr[1];
    float v[8] = {a.x, a.y, a.z, a.w, b.x, b.y, b.z, b.w};
    float ss = 0.f;
#pragma unroll
    for (int j = 0; j < 8; ++j) ss += v[j] * v[j];
#pragma unroll
    for (int o = 32; o > 0; o >>= 1) ss += __shfl_down(ss, o, 64);
    __shared__ float sred[4];
    if ((tid & 63) == 0) sred[tid >> 6] = ss;
    __syncthreads();
    float r = rsqrtf((sred[0] + sred[1] + sred[2] + sred[3]) * (1.f / DMODEL) + 1e-5f);
    const float4* wr = (const float4*)(w + tid * 8);
    float4 wa = wr[0], wb = wr[1];
    float wv[8] = {wa.x, wa.y, wa.z, wa.w, wb.x, wb.y, wb.z, wb.w};
    short8 o8;
#pragma unroll
    for (int j = 0; j < 8; ++j) o8[j] = f2b(v[j] * r * wv[j]);
    *(short8*)(xn + (size_t)t * DMODEL + tid * 8) = o8;
}

// ---------------------------------------------------------------------------
// GEMM C[M,N] = A[M,K] * B[N,K]^T  (bf16 in, fp32 accum), m97 structure.
// Output bf16 or fp32(+fp32 residual).
// ---------------------------------------------------------------------------
template <bool ADD_RES, bool F32OUT>
__global__ __launch_bounds__(256) void gemm_bt(
    const short* __restrict__ A, const short* __restrict__ B,
    const float* __restrict__ RES, void* __restrict__ Cp,
    int M, int N, int K) {
    __shared__ __align__(16) short As[128 * 32];
    __shared__ __align__(16) short Bs[128 * 32];

    const int tid  = threadIdx.x;
    const int wave = tid >> 6;
    const int lane = tid & 63;
    const int lr   = lane & 15;
    const int q    = lane >> 4;
    const int m0   = blockIdx.x * 128;
    const int n0   = blockIdx.y * 128;
    const int wm   = (wave >> 1) * 64;
    const int wn   = (wave & 1) * 64;

    f32x4 acc[4][4] = {};

    for (int k0 = 0; k0 < K; k0 += 32) {
#pragma unroll
        for (int p = 0; p < 2; ++p) {
            int i16 = p * 256 + tid;
            int row = i16 >> 2, ch = i16 & 3;
            const short* ga = A + (size_t)(m0 + row) * K + k0 + ch * 8;
            const short* gb = B + (size_t)(n0 + row) * K + k0 + ch * 8;
            __builtin_amdgcn_global_load_lds(
                (const __attribute__((address_space(1))) void*)ga,
                (__attribute__((address_space(3))) void*)((char*)As + i16 * 16),
                16, 0, 0);
            __builtin_amdgcn_global_load_lds(
                (const __attribute__((address_space(1))) void*)gb,
                (__attribute__((address_space(3))) void*)((char*)Bs + i16 * 16),
                16, 0, 0);
        }
        __syncthreads();

        short8 af[4], bfr[4];
#pragma unroll
        for (int i = 0; i < 4; ++i) {
            af[i]  = *(const short8*)&As[(wm + i * 16 + lr) * 32 + q * 8];
            bfr[i] = *(const short8*)&Bs[(wn + i * 16 + lr) * 32 + q * 8];
        }
#pragma unroll
        for (int i = 0; i < 4; ++i)
#pragma unroll
            for (int j = 0; j < 4; ++j)
                acc[i][j] = __builtin_amdgcn_mfma_f32_16x16x32_bf16(
                    af[i], bfr[j], acc[i][j], 0, 0, 0);
        __syncthreads();
    }

#pragma unroll
    for (int i = 0; i < 4; ++i)
#pragma unroll
        for (int j = 0; j < 4; ++j)
#pragma unroll
            for (int r = 0; r < 4; ++r) {
                int m = m0 + wm + i * 16 + q * 4 + r;
                int n = n0 + wn + j * 16 + lr;
                size_t idx = (size_t)m * N + n;
                float v = acc[i][j][r];
                if (ADD_RES) v += RES[idx];
                if (F32OUT) ((float*)Cp)[idx] = v;
                else        ((short*)Cp)[idx] = f2b(v);
            }
}

// ---------------------------------------------------------------------------
// depthwise causal conv(K=4) + bias + SiLU -> bf16 xc  (weights fp32)
// ---------------------------------------------------------------------------
__global__ __launch_bounds__(256) void conv_silu_kernel(
    const short* __restrict__ xz, const float* __restrict__ cw,
    const float* __restrict__ cb, short* __restrict__ xc) {
    const int t = blockIdx.x;
    const int b = t >> 11, l = t & 2047;
    for (int c = threadIdx.x; c < DINNER; c += 256) {
        float acc = cb[c];
#pragma unroll
        for (int k = 0; k < 4; ++k) {
            int ls = l - 3 + k;
            if (ls >= 0)
                acc += b2f(xz[(size_t)(b * LSEQ + ls) * (2 * DINNER) + c]) *
                       cw[c * 4 + k];
        }
        xc[(size_t)t * DINNER + c] = f2b(acc / (1.f + __expf(-acc)));
    }
}

// ---------------------------------------------------------------------------
// x_proj -> fp32 x_ssm (NTOK x 33); xc bf16, W fp32
// ---------------------------------------------------------------------------
__global__ __launch_bounds__(256) void xproj_kernel(
    const short* __restrict__ xc, const float* __restrict__ W,
    float* __restrict__ out) {
    const int t = blockIdx.x, tid = threadIdx.x;
    float xv[16];
    {
        short8 a = *(const short8*)(xc + (size_t)t * DINNER + tid * 16);
        short8 b = *(const short8*)(xc + (size_t)t * DINNER + tid * 16 + 8);
#pragma unroll
        for (int j = 0; j < 8; ++j) { xv[j] = b2f(a[j]); xv[8 + j] = b2f(b[j]); }
    }
    float acc[33];
#pragma unroll
    for (int e = 0; e < 33; ++e) {
        const float4* wr = (const float4*)(W + (size_t)e * DINNER + tid * 16);
        float4 w0 = wr[0], w1 = wr[1], w2 = wr[2], w3 = wr[3];
        float wv[16] = {w0.x, w0.y, w0.z, w0.w, w1.x, w1.y, w1.z, w1.w,
                        w2.x, w2.y, w2.z, w2.w, w3.x, w3.y, w3.z, w3.w};
        float s = 0.f;
#pragma unroll
        for (int j = 0; j < 16; ++j) s += xv[j] * wv[j];
        acc[e] = s;
    }
    __shared__ float red[4][33];
#pragma unroll
    for (int e = 0; e < 33; ++e) {
        float v = acc[e];
#pragma unroll
        for (int o = 32; o > 0; o >>= 1) v += __shfl_down(v, o, 64);
        if ((tid & 63) == 0) red[tid >> 6][e] = v;
    }
    __syncthreads();
    if (tid < 33)
        out[(size_t)t * 33 + tid] = red[0][tid] + red[1][tid] + red[2][tid] + red[3][tid];
}

// ---------------------------------------------------------------------------
// State-parallel selective scan. One LANE per (chain, state); params fp32.
// Latency fix: software-prefetch ring of depth PF=16. The only true
// cross-step dependency is h (one FMA); all loads (B,C,s32,u,z) are pure
// functions of l and are issued PF steps ahead so the ~900-cycle HBM
// latency amortizes to ~56 cy/step instead of pacing every step.
// ---------------------------------------------------------------------------
#define PF 16
__global__ __launch_bounds__(256) void scan_state_kernel(
    const float* __restrict__ xssm, short* __restrict__ xc,
    const short* __restrict__ xz, const float* __restrict__ dt_w,
    const float* __restrict__ dt_b, const float* __restrict__ A_log,
    const float* __restrict__ D_par) {
    const int tid   = threadIdx.x;
    const int n     = tid & 15;                        // state index
    const int chain = blockIdx.x * 16 + (tid >> 4);    // 16 chains per block
    const int b     = chain >> 12;                     // DINNER=4096
    const int c     = chain & (DINNER - 1);

    const float An  = -__expf(A_log[c * NSTATE + n]);
    const float dtw = dt_w[c];
    const float dtb = dt_b[c];
    const float Dp  = D_par[c];

    const float* rowb = xssm + (size_t)b * LSEQ * 33;
    const short* ub   = xc + (size_t)b * LSEQ * DINNER + c;
    const short* zb   = xz + (size_t)b * LSEQ * (2 * DINNER) + DINNER + c;
    short*       yb   = xc + (size_t)b * LSEQ * DINNER + c;   // in-place y

    // prefetch ring (indices static after full unroll -> stays in VGPRs)
    float Bb[PF], Cb[PF], sb[PF], uu[PF], zz[PF];
#pragma unroll
    for (int i = 0; i < PF; ++i) {
        const float* r = rowb + (size_t)i * 33;
        Bb[i] = r[n]; Cb[i] = r[16 + n]; sb[i] = r[32];
        uu[i] = b2f(ub[(size_t)i * DINNER]);
        zz[i] = b2f(zb[(size_t)i * 2 * DINNER]);
    }

    float h = 0.f;
    for (int l0 = 0; l0 < LSEQ; l0 += PF) {
#pragma unroll
        for (int i = 0; i < PF; ++i) {
            const int l = l0 + i;
            // consume slot i
            const float Bv = Bb[i], Cv = Cb[i], s32 = sb[i];
            const float u = uu[i], z = zz[i];
            // refill slot i with step l+PF (clamped; last block's refills unused)
            int lp = l + PF; if (lp > LSEQ - 1) lp = LSEQ - 1;
            const float* r = rowb + (size_t)lp * 33;
            Bb[i] = r[n]; Cb[i] = r[16 + n]; sb[i] = r[32];
            uu[i] = b2f(ub[(size_t)lp * DINNER]);
            zz[i] = b2f(zb[(size_t)lp * 2 * DINNER]);
            // compute
            float v = s32 * dtw + dtb;
            float dt = (v > 20.f) ? v : __logf(1.f + __expf(v));
            h = __expf(dt * An) * h + (dt * u) * Bv;
            float part = h * Cv;
#pragma unroll
            for (int o = 8; o > 0; o >>= 1) part += __shfl_xor(part, o, 16);
            if (n == 0) {
                float y  = part + Dp * u;
                float zg = z / (1.f + __expf(-z));
                yb[(size_t)l * DINNER] = f2b(y * zg);
            }
        }
    }
}

// ---------------------------------------------------------------------------
extern "C" void kernel_launch(void* const* d_in, const int* in_sizes, int n_in,
                              void* d_out, int out_size, void* d_ws, size_t ws_size,
                              hipStream_t stream) {
    const float* x      = (const float*)d_in[0];
    const float* norm_w = (const float*)d_in[1];
    const float* w_in   = (const float*)d_in[2];   // (8192, 2048)
    const float* conv_w = (const float*)d_in[3];
    const float* conv_b = (const float*)d_in[4];
    const float* w_xp   = (const float*)d_in[5];   // (33, 4096)
    const float* dt_w   = (const float*)d_in[6];
    const float* dt_b   = (const float*)d_in[7];
    const float* A_log  = (const float*)d_in[8];
    const float* D_par  = (const float*)d_in[9];
    const float* w_out  = (const float*)d_in[10];  // (2048, 4096)
    float* out = (float*)d_out;

    char* ws = (char*)d_ws;
    short* wb   = (short*)(ws);                        // 32 MB: w_in bf16, later w_out bf16
    short* xn   = (short*)(ws + (size_t)(32 << 20));   // 16 MB
    short* xz   = (short*)(ws + (size_t)(48 << 20));   // 64 MB
    short* xc   = (short*)(ws + (size_t)(112 << 20));  // 32 MB (y written in place)
    float* xsm  = (float*)(ws + (size_t)(144 << 20));  // 0.55 MB

    // 1. w_in -> bf16
    f32_to_bf16_kernel<<<(2 * DINNER * DMODEL / 8) / 256, 256, 0, stream>>>(
        w_in, wb, 2 * DINNER * DMODEL / 8);
    // 2. RMSNorm
    rmsnorm_kernel<<<NTOK, 256, 0, stream>>>(x, norm_w, xn);
    // 3. in_proj GEMM -> xz bf16
    gemm_bt<false, false><<<dim3(NTOK / 128, 8192 / 128), 256, 0, stream>>>(
        xn, wb, nullptr, xz, NTOK, 2 * DINNER, DMODEL);
    // 4. conv + SiLU -> xc bf16
    conv_silu_kernel<<<NTOK, 256, 0, stream>>>(xz, conv_w, conv_b, xc);
    // 5. x_proj -> xsm fp32
    xproj_kernel<<<NTOK, 256, 0, stream>>>(xc, w_xp, xsm);
    // 6. selective scan (in-place gated y into xc)
    scan_state_kernel<<<NCHAIN / 16, 256, 0, stream>>>(xsm, xc, xz, dt_w, dt_b,
                                                       A_log, D_par);
    // 7. w_out -> bf16 (reuse wb region; w_in copy dead after GEMM1)
    f32_to_bf16_kernel<<<(DMODEL * DINNER / 8) / 256, 256, 0, stream>>>(
        w_out, wb, DMODEL * DINNER / 8);
    // 8. out_proj GEMM + residual -> fp32 out
    gemm_bt<true, true><<<dim3(NTOK / 128, DMODEL / 128), 256, 0, stream>>>(
        xc, wb, x, out, NTOK, DMODEL, DINNER);
}

// Round 2
// 1409.900 us; speedup vs baseline: 1.1449x; 1.0130x over previous
//
#include <hip/hip_runtime.h>

#define NTOK   4096   // BATCH * L
#define LSEQ   2048
#define DMODEL 2048
#define DINNER 4096
#define NSTATE 16
#define NCHAIN 8192   // BATCH * DINNER

using short8 = __attribute__((ext_vector_type(8))) short;
using f32x4  = __attribute__((ext_vector_type(4))) float;

__device__ inline float b2f(short s) {
    union { unsigned u; float f; } v;
    v.u = ((unsigned)(unsigned short)s) << 16;
    return v.f;
}
__device__ inline short f2b(float f) {
    unsigned u = __float_as_uint(f);
    unsigned r = (u + 0x7fffu + ((u >> 16) & 1u)) >> 16;
    return (short)r;
}

// ---------------------------------------------------------------------------
// fp32 -> bf16 bulk convert (8 elems/thread)
// ---------------------------------------------------------------------------
__global__ __launch_bounds__(256) void f32_to_bf16_kernel(
    const float* __restrict__ in, short* __restrict__ out, int n8) {
    int i = blockIdx.x * 256 + threadIdx.x;
    if (i >= n8) return;
    const float4* p = (const float4*)in + 2 * (size_t)i;
    float4 a = p[0], b = p[1];
    short8 s;
    s[0] = f2b(a.x); s[1] = f2b(a.y); s[2] = f2b(a.z); s[3] = f2b(a.w);
    s[4] = f2b(b.x); s[5] = f2b(b.y); s[6] = f2b(b.z); s[7] = f2b(b.w);
    *(short8*)(out + 8 * (size_t)i) = s;
}

// ---------------------------------------------------------------------------
// RMSNorm: x (NTOK x DMODEL fp32) -> xn bf16
// ---------------------------------------------------------------------------
__global__ __launch_bounds__(256) void rmsnorm_kernel(
    const float* __restrict__ x, const float* __restrict__ w,
    short* __restrict__ xn) {
    const int t = blockIdx.x, tid = threadIdx.x;
    const float4* xr = (const float4*)(x + (size_t)t * DMODEL + tid * 8);
    float4 a = xr[0], b = xr[1];
    float v[8] = {a.x, a.y, a.z, a.w, b.x, b.y, b.z, b.w};
    float ss = 0.f;
#pragma unroll
    for (int j = 0; j < 8; ++j) ss += v[j] * v[j];
#pragma unroll
    for (int o = 32; o > 0; o >>= 1) ss += __shfl_down(ss, o, 64);
    __shared__ float sred[4];
    if ((tid & 63) == 0) sred[tid >> 6] = ss;
    __syncthreads();
    float r = rsqrtf((sred[0] + sred[1] + sred[2] + sred[3]) * (1.f / DMODEL) + 1e-5f);
    const float4* wr = (const float4*)(w + tid * 8);
    float4 wa = wr[0], wb = wr[1];
    float wv[8] = {wa.x, wa.y, wa.z, wa.w, wb.x, wb.y, wb.z, wb.w};
    short8 o8;
#pragma unroll
    for (int j = 0; j < 8; ++j) o8[j] = f2b(v[j] * r * wv[j]);
    *(short8*)(xn + (size_t)t * DMODEL + tid * 8) = o8;
}

// ---------------------------------------------------------------------------
// GEMM C[M,N] = A[M,K] * B[N,K]^T  (bf16 in, fp32 accum), m97 structure.
// Output bf16 or fp32(+fp32 residual).
// ---------------------------------------------------------------------------
template <bool ADD_RES, bool F32OUT>
__global__ __launch_bounds__(256) void gemm_bt(
    const short* __restrict__ A, const short* __restrict__ B,
    const float* __restrict__ RES, void* __restrict__ Cp,
    int M, int N, int K) {
    __shared__ __align__(16) short As[128 * 32];
    __shared__ __align__(16) short Bs[128 * 32];

    const int tid  = threadIdx.x;
    const int wave = tid >> 6;
    const int lane = tid & 63;
    const int lr   = lane & 15;
    const int q    = lane >> 4;
    const int m0   = blockIdx.x * 128;
    const int n0   = blockIdx.y * 128;
    const int wm   = (wave >> 1) * 64;
    const int wn   = (wave & 1) * 64;

    f32x4 acc[4][4] = {};

    for (int k0 = 0; k0 < K; k0 += 32) {
#pragma unroll
        for (int p = 0; p < 2; ++p) {
            int i16 = p * 256 + tid;
            int row = i16 >> 2, ch = i16 & 3;
            const short* ga = A + (size_t)(m0 + row) * K + k0 + ch * 8;
            const short* gb = B + (size_t)(n0 + row) * K + k0 + ch * 8;
            __builtin_amdgcn_global_load_lds(
                (const __attribute__((address_space(1))) void*)ga,
                (__attribute__((address_space(3))) void*)((char*)As + i16 * 16),
                16, 0, 0);
            __builtin_amdgcn_global_load_lds(
                (const __attribute__((address_space(1))) void*)gb,
                (__attribute__((address_space(3))) void*)((char*)Bs + i16 * 16),
                16, 0, 0);
        }
        __syncthreads();

        short8 af[4], bfr[4];
#pragma unroll
        for (int i = 0; i < 4; ++i) {
            af[i]  = *(const short8*)&As[(wm + i * 16 + lr) * 32 + q * 8];
            bfr[i] = *(const short8*)&Bs[(wn + i * 16 + lr) * 32 + q * 8];
        }
#pragma unroll
        for (int i = 0; i < 4; ++i)
#pragma unroll
            for (int j = 0; j < 4; ++j)
                acc[i][j] = __builtin_amdgcn_mfma_f32_16x16x32_bf16(
                    af[i], bfr[j], acc[i][j], 0, 0, 0);
        __syncthreads();
    }

#pragma unroll
    for (int i = 0; i < 4; ++i)
#pragma unroll
        for (int j = 0; j < 4; ++j)
#pragma unroll
            for (int r = 0; r < 4; ++r) {
                int m = m0 + wm + i * 16 + q * 4 + r;
                int n = n0 + wn + j * 16 + lr;
                size_t idx = (size_t)m * N + n;
                float v = acc[i][j][r];
                if (ADD_RES) v += RES[idx];
                if (F32OUT) ((float*)Cp)[idx] = v;
                else        ((short*)Cp)[idx] = f2b(v);
            }
}

// ---------------------------------------------------------------------------
// depthwise causal conv(K=4) + bias + SiLU -> bf16 xc  (weights fp32)
// ---------------------------------------------------------------------------
__global__ __launch_bounds__(256) void conv_silu_kernel(
    const short* __restrict__ xz, const float* __restrict__ cw,
    const float* __restrict__ cb, short* __restrict__ xc) {
    const int t = blockIdx.x;
    const int b = t >> 11, l = t & 2047;
    for (int c = threadIdx.x; c < DINNER; c += 256) {
        float acc = cb[c];
#pragma unroll
        for (int k = 0; k < 4; ++k) {
            int ls = l - 3 + k;
            if (ls >= 0)
                acc += b2f(xz[(size_t)(b * LSEQ + ls) * (2 * DINNER) + c]) *
                       cw[c * 4 + k];
        }
        xc[(size_t)t * DINNER + c] = f2b(acc / (1.f + __expf(-acc)));
    }
}

// ---------------------------------------------------------------------------
// x_proj -> transposed outputs: BT[b][n][l], CT[b][n][l], s32T[b][l]
// (same fp32 values as before, layout changed for the scan's vector loads)
// ---------------------------------------------------------------------------
__global__ __launch_bounds__(256) void xproj_kernel(
    const short* __restrict__ xc, const float* __restrict__ W,
    float* __restrict__ BT, float* __restrict__ CT, float* __restrict__ s32T) {
    const int t = blockIdx.x, tid = threadIdx.x;
    float xv[16];
    {
        short8 a = *(const short8*)(xc + (size_t)t * DINNER + tid * 16);
        short8 b = *(const short8*)(xc + (size_t)t * DINNER + tid * 16 + 8);
#pragma unroll
        for (int j = 0; j < 8; ++j) { xv[j] = b2f(a[j]); xv[8 + j] = b2f(b[j]); }
    }
    float acc[33];
#pragma unroll
    for (int e = 0; e < 33; ++e) {
        const float4* wr = (const float4*)(W + (size_t)e * DINNER + tid * 16);
        float4 w0 = wr[0], w1 = wr[1], w2 = wr[2], w3 = wr[3];
        float wv[16] = {w0.x, w0.y, w0.z, w0.w, w1.x, w1.y, w1.z, w1.w,
                        w2.x, w2.y, w2.z, w2.w, w3.x, w3.y, w3.z, w3.w};
        float s = 0.f;
#pragma unroll
        for (int j = 0; j < 16; ++j) s += xv[j] * wv[j];
        acc[e] = s;
    }
    __shared__ float red[4][33];
#pragma unroll
    for (int e = 0; e < 33; ++e) {
        float v = acc[e];
#pragma unroll
        for (int o = 32; o > 0; o >>= 1) v += __shfl_down(v, o, 64);
        if ((tid & 63) == 0) red[tid >> 6][e] = v;
    }
    __syncthreads();
    if (tid < 33) {
        float val = red[0][tid] + red[1][tid] + red[2][tid] + red[3][tid];
        const int bb = t >> 11, l = t & (LSEQ - 1);
        if (tid < 16)
            BT[((size_t)bb * NSTATE + tid) * LSEQ + l] = val;
        else if (tid < 32)
            CT[((size_t)bb * NSTATE + (tid - 16)) * LSEQ + l] = val;
        else
            s32T[(size_t)bb * LSEQ + l] = val;
    }
}

// ---------------------------------------------------------------------------
// LDS tile transpose: xc[b][l][c] (bf16) -> uT[b][c][l] (bf16), 64x64 tiles
// ---------------------------------------------------------------------------
__global__ __launch_bounds__(256) void transpose_xc_kernel(
    const short* __restrict__ xc, short* __restrict__ uT) {
    __shared__ short tile[64][66];
    const int bb = blockIdx.z;
    const int l0 = blockIdx.x * 64;
    const int c0 = blockIdx.y * 64;
    const int tid = threadIdx.x;
    const int rr = tid >> 3;          // 0..31
    const int c8 = (tid & 7) * 8;     // 0..56
#pragma unroll
    for (int p = 0; p < 2; ++p) {
        int r = p * 32 + rr;
        short8 v = *(const short8*)(xc + ((size_t)(bb * LSEQ + l0 + r)) * DINNER + c0 + c8);
#pragma unroll
        for (int j = 0; j < 8; ++j) tile[r][c8 + j] = v[j];
    }
    __syncthreads();
#pragma unroll
    for (int p = 0; p < 2; ++p) {
        int cr = p * 32 + rr;
        short8 v;
#pragma unroll
        for (int j = 0; j < 8; ++j) v[j] = tile[c8 + j][cr];
        *(short8*)(uT + ((size_t)(bb * DINNER + c0 + cr)) * LSEQ + l0 + c8) = v;
    }
}

// ---------------------------------------------------------------------------
// State-parallel selective scan, v3. One LANE per (chain, state).
// B/C/s32 come from transposed L2-hot arrays -> dwordx4 per 4 steps;
// u from transposed uT -> dwordx2 per 4 steps. Only z stays per-step.
// Ring of GQ groups of 4 steps (16-step lookahead). Math is bit-identical
// to v2 (absmax sits at the 0.015625 threshold - do not reorder fp ops).
// ---------------------------------------------------------------------------
#define GQ 4
__global__ __launch_bounds__(256) void scan_state_kernel(
    const float* __restrict__ BT, const float* __restrict__ CT,
    const float* __restrict__ s32T, const short* __restrict__ uT,
    const short* __restrict__ xz, short* __restrict__ yout,
    const float* __restrict__ dt_w, const float* __restrict__ dt_b,
    const float* __restrict__ A_log, const float* __restrict__ D_par) {
    const int tid   = threadIdx.x;
    const int n     = tid & 15;
    const int chain = blockIdx.x * 16 + (tid >> 4);
    const int b     = chain >> 12;
    const int c     = chain & (DINNER - 1);

    const float An  = -__expf(A_log[c * NSTATE + n]);
    const float dtw = dt_w[c];
    const float dtb = dt_b[c];
    const float Dp  = D_par[c];

    const float* Bb = BT + ((size_t)b * NSTATE + n) * LSEQ;
    const float* Cb = CT + ((size_t)b * NSTATE + n) * LSEQ;
    const float* sb = s32T + (size_t)b * LSEQ;
    const short* ub = uT + (size_t)chain * LSEQ;
    const short* zb = xz + (size_t)b * LSEQ * (2 * DINNER) + DINNER + c;
    short*       yb = yout + ((size_t)b * LSEQ) * DINNER + c;

    f32x4 Bq[GQ], Cq[GQ], sq[GQ];
    uint2 uq[GQ];
    float zz[4 * GQ];
#pragma unroll
    for (int g = 0; g < GQ; ++g) {
        Bq[g] = *(const f32x4*)(Bb + g * 4);
        Cq[g] = *(const f32x4*)(Cb + g * 4);
        sq[g] = *(const f32x4*)(sb + g * 4);
        uq[g] = *(const uint2*)(ub + g * 4);
#pragma unroll
        for (int i = 0; i < 4; ++i)
            zz[g * 4 + i] = b2f(zb[(size_t)(g * 4 + i) * (2 * DINNER)]);
    }

    float h = 0.f;
    for (int l0 = 0; l0 < LSEQ; l0 += 16) {
#pragma unroll
        for (int g = 0; g < GQ; ++g) {
            // consume current group into locals
            f32x4 B4 = Bq[g], C4 = Cq[g], s4 = sq[g];
            uint2 u4 = uq[g];
            float zc[4];
#pragma unroll
            for (int i = 0; i < 4; ++i) zc[i] = zz[g * 4 + i];
            // refill slot with group at l0+16 (clamped; clamped loads unused)
            int lp  = l0 + 16 + g * 4;
            int lpc = (lp > LSEQ - 4) ? (LSEQ - 4) : lp;
            Bq[g] = *(const f32x4*)(Bb + lpc);
            Cq[g] = *(const f32x4*)(Cb + lpc);
            sq[g] = *(const f32x4*)(sb + lpc);
            uq[g] = *(const uint2*)(ub + lpc);
#pragma unroll
            for (int i = 0; i < 4; ++i) {
                int lz = lp + i; if (lz > LSEQ - 1) lz = LSEQ - 1;
                zz[g * 4 + i] = b2f(zb[(size_t)lz * (2 * DINNER)]);
            }
            // compute 4 steps
#pragma unroll
            for (int i = 0; i < 4; ++i) {
                const int l = l0 + g * 4 + i;
                const float Bv = B4[i], Cv = C4[i], s32 = s4[i];
                float u;
                {
                    unsigned uw = (i < 2) ? u4.x : u4.y;
                    union { unsigned uu; float ff; } t;
                    t.uu = (i & 1) ? (uw & 0xffff0000u) : (uw << 16);
                    u = t.ff;
                }
                const float z = zc[i];
                float v = s32 * dtw + dtb;
                float dt = (v > 20.f) ? v : __logf(1.f + __expf(v));
                h = __expf(dt * An) * h + (dt * u) * Bv;
                float part = h * Cv;
#pragma unroll
                for (int o = 8; o > 0; o >>= 1) part += __shfl_xor(part, o, 16);
                if (n == 0) {
                    float y  = part + Dp * u;
                    float zg = z / (1.f + __expf(-z));
                    yb[(size_t)l * DINNER] = f2b(y * zg);
                }
            }
        }
    }
}

// ---------------------------------------------------------------------------
extern "C" void kernel_launch(void* const* d_in, const int* in_sizes, int n_in,
                              void* d_out, int out_size, void* d_ws, size_t ws_size,
                              hipStream_t stream) {
    const float* x      = (const float*)d_in[0];
    const float* norm_w = (const float*)d_in[1];
    const float* w_in   = (const float*)d_in[2];   // (8192, 2048)
    const float* conv_w = (const float*)d_in[3];
    const float* conv_b = (const float*)d_in[4];
    const float* w_xp   = (const float*)d_in[5];   // (33, 4096)
    const float* dt_w   = (const float*)d_in[6];
    const float* dt_b   = (const float*)d_in[7];
    const float* A_log  = (const float*)d_in[8];
    const float* D_par  = (const float*)d_in[9];
    const float* w_out  = (const float*)d_in[10];  // (2048, 4096)
    float* out = (float*)d_out;

    char* ws = (char*)d_ws;
    short* wb   = (short*)(ws);                        // 32 MB: w_in bf16; after GEMM1: uT
    short* xn   = (short*)(ws + (size_t)(32 << 20));   // 16 MB: xn; after GEMM1: w_out bf16
    short* xz   = (short*)(ws + (size_t)(48 << 20));   // 64 MB
    short* xc   = (short*)(ws + (size_t)(112 << 20));  // 32 MB (y written in place)
    float* BT   = (float*)(ws + (size_t)(144 << 20));            // 256 KB
    float* CT   = (float*)(ws + (size_t)(144 << 20) + (256 << 10)); // 256 KB
    float* s32T = (float*)(ws + (size_t)(144 << 20) + (512 << 10)); // 16 KB

    // 1. w_in -> bf16
    f32_to_bf16_kernel<<<(2 * DINNER * DMODEL / 8) / 256, 256, 0, stream>>>(
        w_in, wb, 2 * DINNER * DMODEL / 8);
    // 2. RMSNorm
    rmsnorm_kernel<<<NTOK, 256, 0, stream>>>(x, norm_w, xn);
    // 3. in_proj GEMM -> xz bf16
    gemm_bt<false, false><<<dim3(NTOK / 128, 8192 / 128), 256, 0, stream>>>(
        xn, wb, nullptr, xz, NTOK, 2 * DINNER, DMODEL);
    // 4. conv + SiLU -> xc bf16
    conv_silu_kernel<<<NTOK, 256, 0, stream>>>(xz, conv_w, conv_b, xc);
    // 5. x_proj -> BT/CT/s32T (transposed)
    xproj_kernel<<<NTOK, 256, 0, stream>>>(xc, w_xp, BT, CT, s32T);
    // 5b. transpose xc -> uT (into wb region; w_in copy dead after GEMM1)
    transpose_xc_kernel<<<dim3(LSEQ / 64, DINNER / 64, 2), 256, 0, stream>>>(
        xc, wb);
    // 6. selective scan (gated y written into xc)
    scan_state_kernel<<<NCHAIN / 16, 256, 0, stream>>>(
        BT, CT, s32T, wb, xz, xc, dt_w, dt_b, A_log, D_par);
    // 7. w_out -> bf16 into xn region (xn dead after GEMM1)
    f32_to_bf16_kernel<<<(DMODEL * DINNER / 8) / 256, 256, 0, stream>>>(
        w_out, xn, DMODEL * DINNER / 8);
    // 8. out_proj GEMM + residual -> fp32 out
    gemm_bt<true, true><<<dim3(NTOK / 128, DMODEL / 128), 256, 0, stream>>>(
        xc, xn, x, out, NTOK, DMODEL, DINNER);
}

// Round 3
// 1150.573 us; speedup vs baseline: 1.4029x; 1.2254x over previous
//
#include <hip/hip_runtime.h>

#define NTOK   4096   // BATCH * L
#define LSEQ   2048
#define DMODEL 2048
#define DINNER 4096
#define NSTATE 16
#define NCHAIN 8192   // BATCH * DINNER

using short8 = __attribute__((ext_vector_type(8))) short;
using f32x4  = __attribute__((ext_vector_type(4))) float;

__device__ inline float b2f(short s) {
    union { unsigned u; float f; } v;
    v.u = ((unsigned)(unsigned short)s) << 16;
    return v.f;
}
__device__ inline short f2b(float f) {
    unsigned u = __float_as_uint(f);
    unsigned r = (u + 0x7fffu + ((u >> 16) & 1u)) >> 16;
    return (short)r;
}

// ---------------------------------------------------------------------------
// fp32 -> bf16 bulk convert (8 elems/thread)
// ---------------------------------------------------------------------------
__global__ __launch_bounds__(256) void f32_to_bf16_kernel(
    const float* __restrict__ in, short* __restrict__ out, int n8) {
    int i = blockIdx.x * 256 + threadIdx.x;
    if (i >= n8) return;
    const float4* p = (const float4*)in + 2 * (size_t)i;
    float4 a = p[0], b = p[1];
    short8 s;
    s[0] = f2b(a.x); s[1] = f2b(a.y); s[2] = f2b(a.z); s[3] = f2b(a.w);
    s[4] = f2b(b.x); s[5] = f2b(b.y); s[6] = f2b(b.z); s[7] = f2b(b.w);
    *(short8*)(out + 8 * (size_t)i) = s;
}

// ---------------------------------------------------------------------------
// RMSNorm: x (NTOK x DMODEL fp32) -> xn bf16
// ---------------------------------------------------------------------------
__global__ __launch_bounds__(256) void rmsnorm_kernel(
    const float* __restrict__ x, const float* __restrict__ w,
    short* __restrict__ xn) {
    const int t = blockIdx.x, tid = threadIdx.x;
    const float4* xr = (const float4*)(x + (size_t)t * DMODEL + tid * 8);
    float4 a = xr[0], b = xr[1];
    float v[8] = {a.x, a.y, a.z, a.w, b.x, b.y, b.z, b.w};
    float ss = 0.f;
#pragma unroll
    for (int j = 0; j < 8; ++j) ss += v[j] * v[j];
#pragma unroll
    for (int o = 32; o > 0; o >>= 1) ss += __shfl_down(ss, o, 64);
    __shared__ float sred[4];
    if ((tid & 63) == 0) sred[tid >> 6] = ss;
    __syncthreads();
    float r = rsqrtf((sred[0] + sred[1] + sred[2] + sred[3]) * (1.f / DMODEL) + 1e-5f);
    const float4* wr = (const float4*)(w + tid * 8);
    float4 wa = wr[0], wb = wr[1];
    float wv[8] = {wa.x, wa.y, wa.z, wa.w, wb.x, wb.y, wb.z, wb.w};
    short8 o8;
#pragma unroll
    for (int j = 0; j < 8; ++j) o8[j] = f2b(v[j] * r * wv[j]);
    *(short8*)(xn + (size_t)t * DMODEL + tid * 8) = o8;
}

// ---------------------------------------------------------------------------
// GEMM C[M,N] = A[M,K] * B[N,K]^T  (bf16 in, fp32 accum), m97 structure.
// SPLIT: bf16 out into two half-N buffers (row stride DINNER).
// Else: bf16 or fp32(+fp32 residual) single buffer.
// ---------------------------------------------------------------------------
template <bool ADD_RES, bool F32OUT, bool SPLIT>
__global__ __launch_bounds__(256) void gemm_bt(
    const short* __restrict__ A, const short* __restrict__ B,
    const float* __restrict__ RES, void* __restrict__ Cp, void* __restrict__ Cp2,
    int M, int N, int K) {
    __shared__ __align__(16) short As[128 * 32];
    __shared__ __align__(16) short Bs[128 * 32];

    const int tid  = threadIdx.x;
    const int wave = tid >> 6;
    const int lane = tid & 63;
    const int lr   = lane & 15;
    const int q    = lane >> 4;
    const int m0   = blockIdx.x * 128;
    const int n0   = blockIdx.y * 128;
    const int wm   = (wave >> 1) * 64;
    const int wn   = (wave & 1) * 64;

    f32x4 acc[4][4] = {};

    for (int k0 = 0; k0 < K; k0 += 32) {
#pragma unroll
        for (int p = 0; p < 2; ++p) {
            int i16 = p * 256 + tid;
            int row = i16 >> 2, ch = i16 & 3;
            const short* ga = A + (size_t)(m0 + row) * K + k0 + ch * 8;
            const short* gb = B + (size_t)(n0 + row) * K + k0 + ch * 8;
            __builtin_amdgcn_global_load_lds(
                (const __attribute__((address_space(1))) void*)ga,
                (__attribute__((address_space(3))) void*)((char*)As + i16 * 16),
                16, 0, 0);
            __builtin_amdgcn_global_load_lds(
                (const __attribute__((address_space(1))) void*)gb,
                (__attribute__((address_space(3))) void*)((char*)Bs + i16 * 16),
                16, 0, 0);
        }
        __syncthreads();

        short8 af[4], bfr[4];
#pragma unroll
        for (int i = 0; i < 4; ++i) {
            af[i]  = *(const short8*)&As[(wm + i * 16 + lr) * 32 + q * 8];
            bfr[i] = *(const short8*)&Bs[(wn + i * 16 + lr) * 32 + q * 8];
        }
#pragma unroll
        for (int i = 0; i < 4; ++i)
#pragma unroll
            for (int j = 0; j < 4; ++j)
                acc[i][j] = __builtin_amdgcn_mfma_f32_16x16x32_bf16(
                    af[i], bfr[j], acc[i][j], 0, 0, 0);
        __syncthreads();
    }

    // SPLIT: whole block lies in one half (n0 multiple of 128, DINNER mult of 128)
    short* sdst = nullptr;
    int    noff = 0;
    if (SPLIT) {
        bool hi = (n0 >= DINNER);
        sdst = hi ? (short*)Cp2 : (short*)Cp;
        noff = hi ? DINNER : 0;
    }

#pragma unroll
    for (int i = 0; i < 4; ++i)
#pragma unroll
        for (int j = 0; j < 4; ++j)
#pragma unroll
            for (int r = 0; r < 4; ++r) {
                int m = m0 + wm + i * 16 + q * 4 + r;
                int n = n0 + wn + j * 16 + lr;
                float v = acc[i][j][r];
                if (SPLIT) {
                    sdst[(size_t)m * DINNER + (n - noff)] = f2b(v);
                } else {
                    size_t idx = (size_t)m * N + n;
                    if (ADD_RES) v += RES[idx];
                    if (F32OUT) ((float*)Cp)[idx] = v;
                    else        ((short*)Cp)[idx] = f2b(v);
                }
            }
}

// ---------------------------------------------------------------------------
// depthwise causal conv(K=4) + bias + SiLU -> bf16 xc  (reads split Xi buffer)
// ---------------------------------------------------------------------------
__global__ __launch_bounds__(256) void conv_silu_kernel(
    const short* __restrict__ xi, const float* __restrict__ cw,
    const float* __restrict__ cb, short* __restrict__ xc) {
    const int t = blockIdx.x;
    const int b = t >> 11, l = t & 2047;
    for (int c = threadIdx.x; c < DINNER; c += 256) {
        float acc = cb[c];
#pragma unroll
        for (int k = 0; k < 4; ++k) {
            int ls = l - 3 + k;
            if (ls >= 0)
                acc += b2f(xi[(size_t)(b * LSEQ + ls) * DINNER + c]) *
                       cw[c * 4 + k];
        }
        xc[(size_t)t * DINNER + c] = f2b(acc / (1.f + __expf(-acc)));
    }
}

// ---------------------------------------------------------------------------
// x_proj -> transposed outputs: BT[b][n][l], CT[b][n][l], s32T[b][l]
// ---------------------------------------------------------------------------
__global__ __launch_bounds__(256) void xproj_kernel(
    const short* __restrict__ xc, const float* __restrict__ W,
    float* __restrict__ BT, float* __restrict__ CT, float* __restrict__ s32T) {
    const int t = blockIdx.x, tid = threadIdx.x;
    float xv[16];
    {
        short8 a = *(const short8*)(xc + (size_t)t * DINNER + tid * 16);
        short8 b = *(const short8*)(xc + (size_t)t * DINNER + tid * 16 + 8);
#pragma unroll
        for (int j = 0; j < 8; ++j) { xv[j] = b2f(a[j]); xv[8 + j] = b2f(b[j]); }
    }
    float acc[33];
#pragma unroll
    for (int e = 0; e < 33; ++e) {
        const float4* wr = (const float4*)(W + (size_t)e * DINNER + tid * 16);
        float4 w0 = wr[0], w1 = wr[1], w2 = wr[2], w3 = wr[3];
        float wv[16] = {w0.x, w0.y, w0.z, w0.w, w1.x, w1.y, w1.z, w1.w,
                        w2.x, w2.y, w2.z, w2.w, w3.x, w3.y, w3.z, w3.w};
        float s = 0.f;
#pragma unroll
        for (int j = 0; j < 16; ++j) s += xv[j] * wv[j];
        acc[e] = s;
    }
    __shared__ float red[4][33];
#pragma unroll
    for (int e = 0; e < 33; ++e) {
        float v = acc[e];
#pragma unroll
        for (int o = 32; o > 0; o >>= 1) v += __shfl_down(v, o, 64);
        if ((tid & 63) == 0) red[tid >> 6][e] = v;
    }
    __syncthreads();
    if (tid < 33) {
        float val = red[0][tid] + red[1][tid] + red[2][tid] + red[3][tid];
        const int bb = t >> 11, l = t & (LSEQ - 1);
        if (tid < 16)
            BT[((size_t)bb * NSTATE + tid) * LSEQ + l] = val;
        else if (tid < 32)
            CT[((size_t)bb * NSTATE + (tid - 16)) * LSEQ + l] = val;
        else
            s32T[(size_t)bb * LSEQ + l] = val;
    }
}

// ---------------------------------------------------------------------------
// LDS tile transpose: xc[b][l][c] (bf16) -> uT[b][c][l] (bf16), 64x64 tiles
// ---------------------------------------------------------------------------
__global__ __launch_bounds__(256) void transpose_xc_kernel(
    const short* __restrict__ xc, short* __restrict__ uT) {
    __shared__ short tile[64][66];
    const int bb = blockIdx.z;
    const int l0 = blockIdx.x * 64;
    const int c0 = blockIdx.y * 64;
    const int tid = threadIdx.x;
    const int rr = tid >> 3;          // 0..31
    const int c8 = (tid & 7) * 8;     // 0..56
#pragma unroll
    for (int p = 0; p < 2; ++p) {
        int r = p * 32 + rr;
        short8 v = *(const short8*)(xc + ((size_t)(bb * LSEQ + l0 + r)) * DINNER + c0 + c8);
#pragma unroll
        for (int j = 0; j < 8; ++j) tile[r][c8 + j] = v[j];
    }
    __syncthreads();
#pragma unroll
    for (int p = 0; p < 2; ++p) {
        int cr = p * 32 + rr;
        short8 v;
#pragma unroll
        for (int j = 0; j < 8; ++j) v[j] = tile[c8 + j][cr];
        *(short8*)(uT + ((size_t)(bb * DINNER + c0 + cr)) * LSEQ + l0 + c8) = v;
    }
}

// ---------------------------------------------------------------------------
// dt precompute: dt[b][c][l] = softplus(s32T[b][l]*dtw[c]+dtb[c]) fp32,
// bit-identical ops to the old in-scan softplus. Output split across two
// 33.5MB regions (b=0 -> dtT0 in dead Xi space, b=1 -> dtT1 in d_out).
// ---------------------------------------------------------------------------
__global__ __launch_bounds__(256) void dt_kernel(
    const float* __restrict__ s32T, const float* __restrict__ dt_w,
    const float* __restrict__ dt_b, float* __restrict__ dtT0,
    float* __restrict__ dtT1) {
    const int chain = blockIdx.x;
    const int b = chain >> 12;
    const int c = chain & (DINNER - 1);
    const float dtw = dt_w[c], dtb = dt_b[c];
    const float* src = s32T + (size_t)b * LSEQ + threadIdx.x * 8;
    float* dst = (b ? dtT1 : dtT0) + (size_t)c * LSEQ + threadIdx.x * 8;
    float4 s0 = ((const float4*)src)[0], s1 = ((const float4*)src)[1];
    float sv[8] = {s0.x, s0.y, s0.z, s0.w, s1.x, s1.y, s1.z, s1.w};
    float dv[8];
#pragma unroll
    for (int j = 0; j < 8; ++j) {
        float v = sv[j] * dtw + dtb;
        dv[j] = (v > 20.f) ? v : __logf(1.f + __expf(v));
    }
    ((float4*)dst)[0] = make_float4(dv[0], dv[1], dv[2], dv[3]);
    ((float4*)dst)[1] = make_float4(dv[4], dv[5], dv[6], dv[7]);
}

// ---------------------------------------------------------------------------
// State-parallel selective scan, v4. One LANE per (chain, state).
// dt precomputed (no softplus in-loop); butterfly sum lands in all 16 lanes,
// lane n keeps step l0+n -> gate+store done once per 16 steps by all lanes
// (kills the divergent per-step epilogue). Math bit-identical to v2/v3.
// ---------------------------------------------------------------------------
#define GQ 4
__global__ __launch_bounds__(256) void scan_state_kernel(
    const float* __restrict__ BT, const float* __restrict__ CT,
    const float* __restrict__ dtT0, const float* __restrict__ dtT1,
    const short* __restrict__ uT, const short* __restrict__ Z,
    short* __restrict__ yout,
    const float* __restrict__ A_log, const float* __restrict__ D_par) {
    const int tid   = threadIdx.x;
    const int n     = tid & 15;
    const int chain = blockIdx.x * 16 + (tid >> 4);
    const int b     = chain >> 12;
    const int c     = chain & (DINNER - 1);

    const float An = -__expf(A_log[c * NSTATE + n]);
    const float Dp = D_par[c];

    const float* Bb = BT + ((size_t)b * NSTATE + n) * LSEQ;
    const float* Cb = CT + ((size_t)b * NSTATE + n) * LSEQ;
    const float* db = (b ? dtT1 : dtT0) + (size_t)c * LSEQ;
    const short* ub = uT + (size_t)chain * LSEQ;
    const short* ue = ub + n;                                    // epilogue u
    const short* zp = Z + ((size_t)b * LSEQ + n) * DINNER + c;   // epilogue z
    short*       yp = yout + ((size_t)b * LSEQ + n) * DINNER + c;

    f32x4 Bq[GQ], Cq[GQ], dq[GQ];
    uint2 uq[GQ];
#pragma unroll
    for (int g = 0; g < GQ; ++g) {
        Bq[g] = *(const f32x4*)(Bb + g * 4);
        Cq[g] = *(const f32x4*)(Cb + g * 4);
        dq[g] = *(const f32x4*)(db + g * 4);
        uq[g] = *(const uint2*)(ub + g * 4);
    }

    float h = 0.f;
    for (int l0 = 0; l0 < LSEQ; l0 += 16) {
        // epilogue operands for this window (issued early, used after 16 steps)
        const float u_n = b2f(ue[0]);
        const float z_n = b2f(zp[0]);
        float ys = 0.f;
#pragma unroll
        for (int g = 0; g < GQ; ++g) {
            f32x4 B4 = Bq[g], C4 = Cq[g], d4 = dq[g];
            uint2 u4 = uq[g];
            int lp  = l0 + 16 + g * 4;
            int lpc = (lp > LSEQ - 4) ? (LSEQ - 4) : lp;
            Bq[g] = *(const f32x4*)(Bb + lpc);
            Cq[g] = *(const f32x4*)(Cb + lpc);
            dq[g] = *(const f32x4*)(db + lpc);
            uq[g] = *(const uint2*)(ub + lpc);
#pragma unroll
            for (int i = 0; i < 4; ++i) {
                const float Bv = B4[i], Cv = C4[i], dt = d4[i];
                float u;
                {
                    unsigned uw = (i < 2) ? u4.x : u4.y;
                    union { unsigned uu; float ff; } t;
                    t.uu = (i & 1) ? (uw & 0xffff0000u) : (uw << 16);
                    u = t.ff;
                }
                h = __expf(dt * An) * h + (dt * u) * Bv;
                float part = h * Cv;
#pragma unroll
                for (int o = 8; o > 0; o >>= 1) part += __shfl_xor(part, o, 16);
                ys = (n == g * 4 + i) ? part : ys;
            }
        }
        // lane n finishes step l0+n for its chain (all 64 lanes active)
        float y  = ys + Dp * u_n;
        float zg = z_n / (1.f + __expf(-z_n));
        yp[0] = f2b(y * zg);
        ue += 16;
        zp += (size_t)16 * DINNER;
        yp += (size_t)16 * DINNER;
    }
}

// ---------------------------------------------------------------------------
extern "C" void kernel_launch(void* const* d_in, const int* in_sizes, int n_in,
                              void* d_out, int out_size, void* d_ws, size_t ws_size,
                              hipStream_t stream) {
    const float* x      = (const float*)d_in[0];
    const float* norm_w = (const float*)d_in[1];
    const float* w_in   = (const float*)d_in[2];   // (8192, 2048)
    const float* conv_w = (const float*)d_in[3];
    const float* conv_b = (const float*)d_in[4];
    const float* w_xp   = (const float*)d_in[5];   // (33, 4096)
    const float* dt_w   = (const float*)d_in[6];
    const float* dt_b   = (const float*)d_in[7];
    const float* A_log  = (const float*)d_in[8];
    const float* D_par  = (const float*)d_in[9];
    const float* w_out  = (const float*)d_in[10];  // (2048, 4096)
    float* out = (float*)d_out;

    char* ws = (char*)d_ws;
    short* wb   = (short*)(ws);                        // 32 MB: w_in bf16; after GEMM1: uT
    short* xn   = (short*)(ws + (size_t)(32 << 20));   // 16 MB: xn; later w_out bf16
    short* Xi   = (short*)(ws + (size_t)(48 << 20));   // 32 MB: x_inner; later dtT0 (fp32)
    short* Zb   = (short*)(ws + (size_t)(80 << 20));   // 32 MB: z half
    short* xc   = (short*)(ws + (size_t)(112 << 20));  // 32 MB: u; y written in place
    float* BT   = (float*)(ws + (size_t)(144 << 20));               // 256 KB
    float* CT   = (float*)(ws + (size_t)(144 << 20) + (256 << 10)); // 256 KB
    float* s32T = (float*)(ws + (size_t)(144 << 20) + (512 << 10)); // 16 KB
    float* dtT0 = (float*)Xi;     // b=0 half of dt (32 MB, Xi dead after conv)
    float* dtT1 = out;            // b=1 half of dt (d_out dead until final GEMM)

    // 1. w_in -> bf16
    f32_to_bf16_kernel<<<(2 * DINNER * DMODEL / 8) / 256, 256, 0, stream>>>(
        w_in, wb, 2 * DINNER * DMODEL / 8);
    // 2. RMSNorm
    rmsnorm_kernel<<<NTOK, 256, 0, stream>>>(x, norm_w, xn);
    // 3. in_proj GEMM -> split Xi / Zb (bf16)
    gemm_bt<false, false, true><<<dim3(NTOK / 128, 8192 / 128), 256, 0, stream>>>(
        xn, wb, nullptr, Xi, Zb, NTOK, 2 * DINNER, DMODEL);
    // 4. conv + SiLU -> xc bf16
    conv_silu_kernel<<<NTOK, 256, 0, stream>>>(Xi, conv_w, conv_b, xc);
    // 5. x_proj -> BT/CT/s32T (transposed)
    xproj_kernel<<<NTOK, 256, 0, stream>>>(xc, w_xp, BT, CT, s32T);
    // 5b. transpose xc -> uT (into wb region; w_in copy dead after GEMM1)
    transpose_xc_kernel<<<dim3(LSEQ / 64, DINNER / 64, 2), 256, 0, stream>>>(
        xc, wb);
    // 5c. dt precompute (Xi dead after conv; out dead until step 8)
    dt_kernel<<<NCHAIN, 256, 0, stream>>>(s32T, dt_w, dt_b, dtT0, dtT1);
    // 6. selective scan (gated y written into xc)
    scan_state_kernel<<<NCHAIN / 16, 256, 0, stream>>>(
        BT, CT, dtT0, dtT1, wb, Zb, xc, A_log, D_par);
    // 7. w_out -> bf16 into xn region
    f32_to_bf16_kernel<<<(DMODEL * DINNER / 8) / 256, 256, 0, stream>>>(
        w_out, xn, DMODEL * DINNER / 8);
    // 8. out_proj GEMM + residual -> fp32 out (overwrites dtT1 scratch)
    gemm_bt<true, true, false><<<dim3(NTOK / 128, DMODEL / 128), 256, 0, stream>>>(
        xc, xn, x, out, nullptr, NTOK, DMODEL, DINNER);
}

// Round 4
// 1079.961 us; speedup vs baseline: 1.4947x; 1.0654x over previous
//
#include <hip/hip_runtime.h>

#define NTOK   4096   // BATCH * L
#define LSEQ   2048
#define DMODEL 2048
#define DINNER 4096
#define NSTATE 16
#define NCHAIN 8192   // BATCH * DINNER

using short8 = __attribute__((ext_vector_type(8))) short;
using f32x4  = __attribute__((ext_vector_type(4))) float;

__device__ inline float b2f(short s) {
    union { unsigned u; float f; } v;
    v.u = ((unsigned)(unsigned short)s) << 16;
    return v.f;
}
__device__ inline short f2b(float f) {
    unsigned u = __float_as_uint(f);
    unsigned r = (u + 0x7fffu + ((u >> 16) & 1u)) >> 16;
    return (short)r;
}

// lane^8 / lane^4 via ds_swizzle BitMode (identical movement to shfl_xor w16)
template <int OFF>
__device__ inline float swz(float v) {
    return __int_as_float(__builtin_amdgcn_ds_swizzle(__float_as_int(v), OFF));
}
// lane^2 / lane^1 via quad_perm DPP (VALU latency, no LDS)
template <int CTRL>
__device__ inline float qperm(float v) {
    return __int_as_float(
        __builtin_amdgcn_mov_dpp(__float_as_int(v), CTRL, 0xF, 0xF, true));
}

// ---------------------------------------------------------------------------
// fp32 -> bf16 bulk convert (8 elems/thread)
// ---------------------------------------------------------------------------
__global__ __launch_bounds__(256) void f32_to_bf16_kernel(
    const float* __restrict__ in, short* __restrict__ out, int n8) {
    int i = blockIdx.x * 256 + threadIdx.x;
    if (i >= n8) return;
    const float4* p = (const float4*)in + 2 * (size_t)i;
    float4 a = p[0], b = p[1];
    short8 s;
    s[0] = f2b(a.x); s[1] = f2b(a.y); s[2] = f2b(a.z); s[3] = f2b(a.w);
    s[4] = f2b(b.x); s[5] = f2b(b.y); s[6] = f2b(b.z); s[7] = f2b(b.w);
    *(short8*)(out + 8 * (size_t)i) = s;
}

// ---------------------------------------------------------------------------
// RMSNorm: x (NTOK x DMODEL fp32) -> xn bf16
// ---------------------------------------------------------------------------
__global__ __launch_bounds__(256) void rmsnorm_kernel(
    const float* __restrict__ x, const float* __restrict__ w,
    short* __restrict__ xn) {
    const int t = blockIdx.x, tid = threadIdx.x;
    const float4* xr = (const float4*)(x + (size_t)t * DMODEL + tid * 8);
    float4 a = xr[0], b = xr[1];
    float v[8] = {a.x, a.y, a.z, a.w, b.x, b.y, b.z, b.w};
    float ss = 0.f;
#pragma unroll
    for (int j = 0; j < 8; ++j) ss += v[j] * v[j];
#pragma unroll
    for (int o = 32; o > 0; o >>= 1) ss += __shfl_down(ss, o, 64);
    __shared__ float sred[4];
    if ((tid & 63) == 0) sred[tid >> 6] = ss;
    __syncthreads();
    float r = rsqrtf((sred[0] + sred[1] + sred[2] + sred[3]) * (1.f / DMODEL) + 1e-5f);
    const float4* wr = (const float4*)(w + tid * 8);
    float4 wa = wr[0], wb = wr[1];
    float wv[8] = {wa.x, wa.y, wa.z, wa.w, wb.x, wb.y, wb.z, wb.w};
    short8 o8;
#pragma unroll
    for (int j = 0; j < 8; ++j) o8[j] = f2b(v[j] * r * wv[j]);
    *(short8*)(xn + (size_t)t * DMODEL + tid * 8) = o8;
}

// ---------------------------------------------------------------------------
// GEMM C[M,N] = A[M,K] * B[N,K]^T  (bf16 in, fp32 accum), m97 structure.
// SPLIT: bf16 out into two half-N buffers (row stride DINNER).
// Else: bf16 or fp32(+fp32 residual) single buffer.
// ---------------------------------------------------------------------------
template <bool ADD_RES, bool F32OUT, bool SPLIT>
__global__ __launch_bounds__(256) void gemm_bt(
    const short* __restrict__ A, const short* __restrict__ B,
    const float* __restrict__ RES, void* __restrict__ Cp, void* __restrict__ Cp2,
    int M, int N, int K) {
    __shared__ __align__(16) short As[128 * 32];
    __shared__ __align__(16) short Bs[128 * 32];

    const int tid  = threadIdx.x;
    const int wave = tid >> 6;
    const int lane = tid & 63;
    const int lr   = lane & 15;
    const int q    = lane >> 4;
    const int m0   = blockIdx.x * 128;
    const int n0   = blockIdx.y * 128;
    const int wm   = (wave >> 1) * 64;
    const int wn   = (wave & 1) * 64;

    f32x4 acc[4][4] = {};

    for (int k0 = 0; k0 < K; k0 += 32) {
#pragma unroll
        for (int p = 0; p < 2; ++p) {
            int i16 = p * 256 + tid;
            int row = i16 >> 2, ch = i16 & 3;
            const short* ga = A + (size_t)(m0 + row) * K + k0 + ch * 8;
            const short* gb = B + (size_t)(n0 + row) * K + k0 + ch * 8;
            __builtin_amdgcn_global_load_lds(
                (const __attribute__((address_space(1))) void*)ga,
                (__attribute__((address_space(3))) void*)((char*)As + i16 * 16),
                16, 0, 0);
            __builtin_amdgcn_global_load_lds(
                (const __attribute__((address_space(1))) void*)gb,
                (__attribute__((address_space(3))) void*)((char*)Bs + i16 * 16),
                16, 0, 0);
        }
        __syncthreads();

        short8 af[4], bfr[4];
#pragma unroll
        for (int i = 0; i < 4; ++i) {
            af[i]  = *(const short8*)&As[(wm + i * 16 + lr) * 32 + q * 8];
            bfr[i] = *(const short8*)&Bs[(wn + i * 16 + lr) * 32 + q * 8];
        }
#pragma unroll
        for (int i = 0; i < 4; ++i)
#pragma unroll
            for (int j = 0; j < 4; ++j)
                acc[i][j] = __builtin_amdgcn_mfma_f32_16x16x32_bf16(
                    af[i], bfr[j], acc[i][j], 0, 0, 0);
        __syncthreads();
    }

    short* sdst = nullptr;
    int    noff = 0;
    if (SPLIT) {
        bool hi = (n0 >= DINNER);
        sdst = hi ? (short*)Cp2 : (short*)Cp;
        noff = hi ? DINNER : 0;
    }

#pragma unroll
    for (int i = 0; i < 4; ++i)
#pragma unroll
        for (int j = 0; j < 4; ++j)
#pragma unroll
            for (int r = 0; r < 4; ++r) {
                int m = m0 + wm + i * 16 + q * 4 + r;
                int n = n0 + wn + j * 16 + lr;
                float v = acc[i][j][r];
                if (SPLIT) {
                    sdst[(size_t)m * DINNER + (n - noff)] = f2b(v);
                } else {
                    size_t idx = (size_t)m * N + n;
                    if (ADD_RES) v += RES[idx];
                    if (F32OUT) ((float*)Cp)[idx] = v;
                    else        ((short*)Cp)[idx] = f2b(v);
                }
            }
}

// ---------------------------------------------------------------------------
// Fused depthwise causal conv(K=4)+bias+SiLU -> xc[b][l][c] AND uT[b][c][l].
// 64x64 (l,c) tile per block, staged through LDS. Conv math per element is
// bit-identical to the old conv_silu_kernel (same k-order adds; halo rows
// zero-filled; x+0.0f is exact).
// ---------------------------------------------------------------------------
__global__ __launch_bounds__(256) void conv_silu_t_kernel(
    const short* __restrict__ xi, const float* __restrict__ cw,
    const float* __restrict__ cb, short* __restrict__ xc,
    short* __restrict__ uT) {
    __shared__ short tin[67][72];
    __shared__ short tout[64][72];
    const int bb = blockIdx.z;
    const int l0 = blockIdx.x * 64;
    const int c0 = blockIdx.y * 64;
    const int tid = threadIdx.x;

    // load 67 rows (ls = l0-3 .. l0+63) x 64 cols
    for (int idx = tid; idx < 67 * 8; idx += 256) {
        int row = idx >> 3, cs = (idx & 7) * 8;
        int ls = l0 - 3 + row;
        short8 v;
        if (ls >= 0) {
            v = *(const short8*)(xi + ((size_t)(bb * LSEQ + ls)) * DINNER + c0 + cs);
        } else {
#pragma unroll
            for (int j = 0; j < 8; ++j) v[j] = 0;
        }
        *(short8*)&tin[row][cs] = v;
    }
    __syncthreads();

    // each thread: one output row r, 16 cols
    const int r   = tid >> 2;
    const int cb16 = (tid & 3) * 16;
    short8 a[4][2];
#pragma unroll
    for (int k = 0; k < 4; ++k) {
        a[k][0] = *(const short8*)&tin[r + k][cb16];
        a[k][1] = *(const short8*)&tin[r + k][cb16 + 8];
    }
    short o16[16];
#pragma unroll
    for (int j = 0; j < 16; ++j) {
        const int c = c0 + cb16 + j;
        float4 w4 = *(const float4*)(cw + (size_t)c * 4);
        float acc = cb[c];
        acc += b2f(a[0][j >> 3][j & 7]) * w4.x;
        acc += b2f(a[1][j >> 3][j & 7]) * w4.y;
        acc += b2f(a[2][j >> 3][j & 7]) * w4.z;
        acc += b2f(a[3][j >> 3][j & 7]) * w4.w;
        o16[j] = f2b(acc / (1.f + __expf(-acc)));
    }
    // write xc row-major
    {
        short8 lo, hi;
#pragma unroll
        for (int j = 0; j < 8; ++j) { lo[j] = o16[j]; hi[j] = o16[8 + j]; }
        short* dst = xc + ((size_t)(bb * LSEQ + l0 + r)) * DINNER + c0 + cb16;
        *(short8*)dst = lo;
        *(short8*)(dst + 8) = hi;
    }
    // stage for transpose
#pragma unroll
    for (int j = 0; j < 16; ++j) tout[r][cb16 + j] = o16[j];
    __syncthreads();

    // transposed write: uT[b][c][l]
    const int rr = tid >> 3;          // 0..31
    const int l8 = (tid & 7) * 8;     // 0..56
#pragma unroll
    for (int p = 0; p < 2; ++p) {
        int cr = p * 32 + rr;
        short8 v;
#pragma unroll
        for (int j = 0; j < 8; ++j) v[j] = tout[l8 + j][cr];
        *(short8*)(uT + ((size_t)(bb * DINNER + c0 + cr)) * LSEQ + l0 + l8) = v;
    }
}

// ---------------------------------------------------------------------------
// x_proj -> transposed outputs: BT[b][n][l], CT[b][n][l], s32T[b][l].
// 2 tokens per block (halves L2 W-traffic); per-token math bit-identical.
// ---------------------------------------------------------------------------
__global__ __launch_bounds__(256) void xproj_kernel(
    const short* __restrict__ xc, const float* __restrict__ W,
    float* __restrict__ BT, float* __restrict__ CT, float* __restrict__ s32T) {
    const int t0 = blockIdx.x * 2, tid = threadIdx.x;
    float xv0[16], xv1[16];
    {
        short8 a = *(const short8*)(xc + (size_t)t0 * DINNER + tid * 16);
        short8 b = *(const short8*)(xc + (size_t)t0 * DINNER + tid * 16 + 8);
        short8 c = *(const short8*)(xc + (size_t)(t0 + 1) * DINNER + tid * 16);
        short8 d = *(const short8*)(xc + (size_t)(t0 + 1) * DINNER + tid * 16 + 8);
#pragma unroll
        for (int j = 0; j < 8; ++j) {
            xv0[j] = b2f(a[j]); xv0[8 + j] = b2f(b[j]);
            xv1[j] = b2f(c[j]); xv1[8 + j] = b2f(d[j]);
        }
    }
    float acc0[33], acc1[33];
#pragma unroll
    for (int e = 0; e < 33; ++e) {
        const float4* wr = (const float4*)(W + (size_t)e * DINNER + tid * 16);
        float4 w0 = wr[0], w1 = wr[1], w2 = wr[2], w3 = wr[3];
        float wv[16] = {w0.x, w0.y, w0.z, w0.w, w1.x, w1.y, w1.z, w1.w,
                        w2.x, w2.y, w2.z, w2.w, w3.x, w3.y, w3.z, w3.w};
        float s0 = 0.f, s1 = 0.f;
#pragma unroll
        for (int j = 0; j < 16; ++j) { s0 += xv0[j] * wv[j]; s1 += xv1[j] * wv[j]; }
        acc0[e] = s0; acc1[e] = s1;
    }
    __shared__ float red[4][33];
#pragma unroll
    for (int tk = 0; tk < 2; ++tk) {
#pragma unroll
        for (int e = 0; e < 33; ++e) {
            float v = tk ? acc1[e] : acc0[e];
#pragma unroll
            for (int o = 32; o > 0; o >>= 1) v += __shfl_down(v, o, 64);
            if ((tid & 63) == 0) red[tid >> 6][e] = v;
        }
        __syncthreads();
        if (tid < 33) {
            float val = red[0][tid] + red[1][tid] + red[2][tid] + red[3][tid];
            const int t = t0 + tk;
            const int bb = t >> 11, l = t & (LSEQ - 1);
            if (tid < 16)
                BT[((size_t)bb * NSTATE + tid) * LSEQ + l] = val;
            else if (tid < 32)
                CT[((size_t)bb * NSTATE + (tid - 16)) * LSEQ + l] = val;
            else
                s32T[(size_t)bb * LSEQ + l] = val;
        }
        __syncthreads();
    }
}

// ---------------------------------------------------------------------------
// dt precompute: dt[b][c][l] = softplus(s32T[b][l]*dtw[c]+dtb[c]) fp32.
// ---------------------------------------------------------------------------
__global__ __launch_bounds__(256) void dt_kernel(
    const float* __restrict__ s32T, const float* __restrict__ dt_w,
    const float* __restrict__ dt_b, float* __restrict__ dtT0,
    float* __restrict__ dtT1) {
    const int chain = blockIdx.x;
    const int b = chain >> 12;
    const int c = chain & (DINNER - 1);
    const float dtw = dt_w[c], dtb = dt_b[c];
    const float* src = s32T + (size_t)b * LSEQ + threadIdx.x * 8;
    float* dst = (b ? dtT1 : dtT0) + (size_t)c * LSEQ + threadIdx.x * 8;
    float4 s0 = ((const float4*)src)[0], s1 = ((const float4*)src)[1];
    float sv[8] = {s0.x, s0.y, s0.z, s0.w, s1.x, s1.y, s1.z, s1.w};
    float dv[8];
#pragma unroll
    for (int j = 0; j < 8; ++j) {
        float v = sv[j] * dtw + dtb;
        dv[j] = (v > 20.f) ? v : __logf(1.f + __expf(v));
    }
    ((float4*)dst)[0] = make_float4(dv[0], dv[1], dv[2], dv[3]);
    ((float4*)dst)[1] = make_float4(dv[4], dv[5], dv[6], dv[7]);
}

// ---------------------------------------------------------------------------
// State-parallel selective scan, v5. One LANE per (chain, state).
// The 4-step group computes h/part first, then runs the 16-lane butterfly
// BATCHED across the 4 steps (4 swizzles in flight per stage) with the
// xor2/xor1 stages as quad_perm DPP (VALU). Same xor order (8,4,2,1) and
// same add operand order as v4 -> bit-identical results.
// ---------------------------------------------------------------------------
#define GQ 4
__global__ __launch_bounds__(256) void scan_state_kernel(
    const float* __restrict__ BT, const float* __restrict__ CT,
    const float* __restrict__ dtT0, const float* __restrict__ dtT1,
    const short* __restrict__ uT, const short* __restrict__ Z,
    short* __restrict__ yout,
    const float* __restrict__ A_log, const float* __restrict__ D_par) {
    const int tid   = threadIdx.x;
    const int n     = tid & 15;
    const int chain = blockIdx.x * 16 + (tid >> 4);
    const int b     = chain >> 12;
    const int c     = chain & (DINNER - 1);

    const float An = -__expf(A_log[c * NSTATE + n]);
    const float Dp = D_par[c];

    const float* Bb = BT + ((size_t)b * NSTATE + n) * LSEQ;
    const float* Cb = CT + ((size_t)b * NSTATE + n) * LSEQ;
    const float* db = (b ? dtT1 : dtT0) + (size_t)c * LSEQ;
    const short* ub = uT + (size_t)chain * LSEQ;
    const short* ue = ub + n;                                    // epilogue u
    const short* zp = Z + ((size_t)b * LSEQ + n) * DINNER + c;   // epilogue z
    short*       yp = yout + ((size_t)b * LSEQ + n) * DINNER + c;

    f32x4 Bq[GQ], Cq[GQ], dq[GQ];
    uint2 uq[GQ];
#pragma unroll
    for (int g = 0; g < GQ; ++g) {
        Bq[g] = *(const f32x4*)(Bb + g * 4);
        Cq[g] = *(const f32x4*)(Cb + g * 4);
        dq[g] = *(const f32x4*)(db + g * 4);
        uq[g] = *(const uint2*)(ub + g * 4);
    }

    float h = 0.f;
    for (int l0 = 0; l0 < LSEQ; l0 += 16) {
        const float u_n = b2f(ue[0]);
        const float z_n = b2f(zp[0]);
        float ys = 0.f;
#pragma unroll
        for (int g = 0; g < GQ; ++g) {
            f32x4 B4 = Bq[g], C4 = Cq[g], d4 = dq[g];
            uint2 u4 = uq[g];
            int lp  = l0 + 16 + g * 4;
            int lpc = (lp > LSEQ - 4) ? (LSEQ - 4) : lp;
            Bq[g] = *(const f32x4*)(Bb + lpc);
            Cq[g] = *(const f32x4*)(Cb + lpc);
            dq[g] = *(const f32x4*)(db + lpc);
            uq[g] = *(const uint2*)(ub + lpc);

            float uv[4], e[4];
#pragma unroll
            for (int i = 0; i < 4; ++i) {
                unsigned uw = (i < 2) ? u4.x : u4.y;
                union { unsigned uu; float ff; } t;
                t.uu = (i & 1) ? (uw & 0xffff0000u) : (uw << 16);
                uv[i] = t.ff;
                e[i]  = __expf(d4[i] * An);
            }
            float part[4];
#pragma unroll
            for (int i = 0; i < 4; ++i) {
                h = e[i] * h + (d4[i] * uv[i]) * B4[i];
                part[i] = h * C4[i];
            }
            float tmp[4];
#pragma unroll
            for (int i = 0; i < 4; ++i) tmp[i] = swz<0x201F>(part[i]);  // ^8
#pragma unroll
            for (int i = 0; i < 4; ++i) part[i] += tmp[i];
#pragma unroll
            for (int i = 0; i < 4; ++i) tmp[i] = swz<0x101F>(part[i]);  // ^4
#pragma unroll
            for (int i = 0; i < 4; ++i) part[i] += tmp[i];
#pragma unroll
            for (int i = 0; i < 4; ++i) part[i] += qperm<0x4E>(part[i]); // ^2
#pragma unroll
            for (int i = 0; i < 4; ++i) part[i] += qperm<0xB1>(part[i]); // ^1
#pragma unroll
            for (int i = 0; i < 4; ++i) ys = (n == g * 4 + i) ? part[i] : ys;
        }
        float y  = ys + Dp * u_n;
        float zg = z_n / (1.f + __expf(-z_n));
        yp[0] = f2b(y * zg);
        ue += 16;
        zp += (size_t)16 * DINNER;
        yp += (size_t)16 * DINNER;
    }
}

// ---------------------------------------------------------------------------
extern "C" void kernel_launch(void* const* d_in, const int* in_sizes, int n_in,
                              void* d_out, int out_size, void* d_ws, size_t ws_size,
                              hipStream_t stream) {
    const float* x      = (const float*)d_in[0];
    const float* norm_w = (const float*)d_in[1];
    const float* w_in   = (const float*)d_in[2];   // (8192, 2048)
    const float* conv_w = (const float*)d_in[3];
    const float* conv_b = (const float*)d_in[4];
    const float* w_xp   = (const float*)d_in[5];   // (33, 4096)
    const float* dt_w   = (const float*)d_in[6];
    const float* dt_b   = (const float*)d_in[7];
    const float* A_log  = (const float*)d_in[8];
    const float* D_par  = (const float*)d_in[9];
    const float* w_out  = (const float*)d_in[10];  // (2048, 4096)
    float* out = (float*)d_out;

    char* ws = (char*)d_ws;
    short* wb   = (short*)(ws);                        // 32 MB: w_in bf16; after GEMM1: uT
    short* xn   = (short*)(ws + (size_t)(32 << 20));   // 16 MB: xn; later w_out bf16
    short* Xi   = (short*)(ws + (size_t)(48 << 20));   // 32 MB: x_inner; later dtT0 (fp32)
    short* Zb   = (short*)(ws + (size_t)(80 << 20));   // 32 MB: z half
    short* xc   = (short*)(ws + (size_t)(112 << 20));  // 32 MB: u; y written in place
    float* BT   = (float*)(ws + (size_t)(144 << 20));               // 256 KB
    float* CT   = (float*)(ws + (size_t)(144 << 20) + (256 << 10)); // 256 KB
    float* s32T = (float*)(ws + (size_t)(144 << 20) + (512 << 10)); // 16 KB
    float* dtT0 = (float*)Xi;     // b=0 half of dt (32 MB, Xi dead after conv)
    float* dtT1 = out;            // b=1 half of dt (d_out dead until final GEMM)

    // 1. w_in -> bf16
    f32_to_bf16_kernel<<<(2 * DINNER * DMODEL / 8) / 256, 256, 0, stream>>>(
        w_in, wb, 2 * DINNER * DMODEL / 8);
    // 2. RMSNorm
    rmsnorm_kernel<<<NTOK, 256, 0, stream>>>(x, norm_w, xn);
    // 3. in_proj GEMM -> split Xi / Zb (bf16)
    gemm_bt<false, false, true><<<dim3(NTOK / 128, 8192 / 128), 256, 0, stream>>>(
        xn, wb, nullptr, Xi, Zb, NTOK, 2 * DINNER, DMODEL);
    // 4. fused conv + SiLU + transpose -> xc (row-major) and uT (into wb)
    conv_silu_t_kernel<<<dim3(LSEQ / 64, DINNER / 64, 2), 256, 0, stream>>>(
        Xi, conv_w, conv_b, xc, wb);
    // 5. x_proj -> BT/CT/s32T (transposed), 2 tokens/block
    xproj_kernel<<<NTOK / 2, 256, 0, stream>>>(xc, w_xp, BT, CT, s32T);
    // 5c. dt precompute (Xi dead after conv; out dead until step 8)
    dt_kernel<<<NCHAIN, 256, 0, stream>>>(s32T, dt_w, dt_b, dtT0, dtT1);
    // 6. selective scan (gated y written into xc)
    scan_state_kernel<<<NCHAIN / 16, 256, 0, stream>>>(
        BT, CT, dtT0, dtT1, wb, Zb, xc, A_log, D_par);
    // 7. w_out -> bf16 into xn region
    f32_to_bf16_kernel<<<(DMODEL * DINNER / 8) / 256, 256, 0, stream>>>(
        w_out, xn, DMODEL * DINNER / 8);
    // 8. out_proj GEMM + residual -> fp32 out (overwrites dtT1 scratch)
    gemm_bt<true, true, false><<<dim3(NTOK / 128, DMODEL / 128), 256, 0, stream>>>(
        xc, xn, x, out, nullptr, NTOK, DMODEL, DINNER);
}

// Round 5
// 1015.936 us; speedup vs baseline: 1.5889x; 1.0630x over previous
//
#include <hip/hip_runtime.h>

#define NTOK   4096   // BATCH * L
#define LSEQ   2048
#define DMODEL 2048
#define DINNER 4096
#define NSTATE 16
#define NCHAIN 8192   // BATCH * DINNER

using short8 = __attribute__((ext_vector_type(8))) short;
using f32x4  = __attribute__((ext_vector_type(4))) float;

__device__ inline float b2f(short s) {
    union { unsigned u; float f; } v;
    v.u = ((unsigned)(unsigned short)s) << 16;
    return v.f;
}
__device__ inline short f2b(float f) {
    unsigned u = __float_as_uint(f);
    unsigned r = (u + 0x7fffu + ((u >> 16) & 1u)) >> 16;
    return (short)r;
}

// lane^4 via ds_swizzle BitMode (identical movement to shfl_xor w16 stage)
template <int OFF>
__device__ inline float swz(float v) {
    return __int_as_float(__builtin_amdgcn_ds_swizzle(__float_as_int(v), OFF));
}
// lane^2 / lane^1 via quad_perm DPP (VALU latency, no LDS)
template <int CTRL>
__device__ inline float qperm(float v) {
    return __int_as_float(
        __builtin_amdgcn_mov_dpp(__float_as_int(v), CTRL, 0xF, 0xF, true));
}
// lane^8 within 16-lane row via DPP row_ror:8 ((i+8)&15 == i^8)
__device__ inline float ror8(float v) {
    return __int_as_float(
        __builtin_amdgcn_mov_dpp(__float_as_int(v), 0x128, 0xF, 0xF, true));
}

// ---------------------------------------------------------------------------
// fp32 -> bf16 bulk convert (8 elems/thread)
// ---------------------------------------------------------------------------
__global__ __launch_bounds__(256) void f32_to_bf16_kernel(
    const float* __restrict__ in, short* __restrict__ out, int n8) {
    int i = blockIdx.x * 256 + threadIdx.x;
    if (i >= n8) return;
    const float4* p = (const float4*)in + 2 * (size_t)i;
    float4 a = p[0], b = p[1];
    short8 s;
    s[0] = f2b(a.x); s[1] = f2b(a.y); s[2] = f2b(a.z); s[3] = f2b(a.w);
    s[4] = f2b(b.x); s[5] = f2b(b.y); s[6] = f2b(b.z); s[7] = f2b(b.w);
    *(short8*)(out + 8 * (size_t)i) = s;
}

// ---------------------------------------------------------------------------
// RMSNorm: x (NTOK x DMODEL fp32) -> xn bf16
// ---------------------------------------------------------------------------
__global__ __launch_bounds__(256) void rmsnorm_kernel(
    const float* __restrict__ x, const float* __restrict__ w,
    short* __restrict__ xn) {
    const int t = blockIdx.x, tid = threadIdx.x;
    const float4* xr = (const float4*)(x + (size_t)t * DMODEL + tid * 8);
    float4 a = xr[0], b = xr[1];
    float v[8] = {a.x, a.y, a.z, a.w, b.x, b.y, b.z, b.w};
    float ss = 0.f;
#pragma unroll
    for (int j = 0; j < 8; ++j) ss += v[j] * v[j];
#pragma unroll
    for (int o = 32; o > 0; o >>= 1) ss += __shfl_down(ss, o, 64);
    __shared__ float sred[4];
    if ((tid & 63) == 0) sred[tid >> 6] = ss;
    __syncthreads();
    float r = rsqrtf((sred[0] + sred[1] + sred[2] + sred[3]) * (1.f / DMODEL) + 1e-5f);
    const float4* wr = (const float4*)(w + tid * 8);
    float4 wa = wr[0], wb = wr[1];
    float wv[8] = {wa.x, wa.y, wa.z, wa.w, wb.x, wb.y, wb.z, wb.w};
    short8 o8;
#pragma unroll
    for (int j = 0; j < 8; ++j) o8[j] = f2b(v[j] * r * wv[j]);
    *(short8*)(xn + (size_t)t * DMODEL + tid * 8) = o8;
}

// ---------------------------------------------------------------------------
// GEMM C[M,N] = A[M,K] * B[N,K]^T  (bf16 in, fp32 accum), m97 structure.
// SPLIT: bf16 out into two half-N buffers (row stride DINNER).
// Else: bf16 or fp32(+fp32 residual) single buffer.
// ---------------------------------------------------------------------------
template <bool ADD_RES, bool F32OUT, bool SPLIT>
__global__ __launch_bounds__(256) void gemm_bt(
    const short* __restrict__ A, const short* __restrict__ B,
    const float* __restrict__ RES, void* __restrict__ Cp, void* __restrict__ Cp2,
    int M, int N, int K) {
    __shared__ __align__(16) short As[128 * 32];
    __shared__ __align__(16) short Bs[128 * 32];

    const int tid  = threadIdx.x;
    const int wave = tid >> 6;
    const int lane = tid & 63;
    const int lr   = lane & 15;
    const int q    = lane >> 4;
    const int m0   = blockIdx.x * 128;
    const int n0   = blockIdx.y * 128;
    const int wm   = (wave >> 1) * 64;
    const int wn   = (wave & 1) * 64;

    f32x4 acc[4][4] = {};

    for (int k0 = 0; k0 < K; k0 += 32) {
#pragma unroll
        for (int p = 0; p < 2; ++p) {
            int i16 = p * 256 + tid;
            int row = i16 >> 2, ch = i16 & 3;
            const short* ga = A + (size_t)(m0 + row) * K + k0 + ch * 8;
            const short* gb = B + (size_t)(n0 + row) * K + k0 + ch * 8;
            __builtin_amdgcn_global_load_lds(
                (const __attribute__((address_space(1))) void*)ga,
                (__attribute__((address_space(3))) void*)((char*)As + i16 * 16),
                16, 0, 0);
            __builtin_amdgcn_global_load_lds(
                (const __attribute__((address_space(1))) void*)gb,
                (__attribute__((address_space(3))) void*)((char*)Bs + i16 * 16),
                16, 0, 0);
        }
        __syncthreads();

        short8 af[4], bfr[4];
#pragma unroll
        for (int i = 0; i < 4; ++i) {
            af[i]  = *(const short8*)&As[(wm + i * 16 + lr) * 32 + q * 8];
            bfr[i] = *(const short8*)&Bs[(wn + i * 16 + lr) * 32 + q * 8];
        }
#pragma unroll
        for (int i = 0; i < 4; ++i)
#pragma unroll
            for (int j = 0; j < 4; ++j)
                acc[i][j] = __builtin_amdgcn_mfma_f32_16x16x32_bf16(
                    af[i], bfr[j], acc[i][j], 0, 0, 0);
        __syncthreads();
    }

    short* sdst = nullptr;
    int    noff = 0;
    if (SPLIT) {
        bool hi = (n0 >= DINNER);
        sdst = hi ? (short*)Cp2 : (short*)Cp;
        noff = hi ? DINNER : 0;
    }

#pragma unroll
    for (int i = 0; i < 4; ++i)
#pragma unroll
        for (int j = 0; j < 4; ++j)
#pragma unroll
            for (int r = 0; r < 4; ++r) {
                int m = m0 + wm + i * 16 + q * 4 + r;
                int n = n0 + wn + j * 16 + lr;
                float v = acc[i][j][r];
                if (SPLIT) {
                    sdst[(size_t)m * DINNER + (n - noff)] = f2b(v);
                } else {
                    size_t idx = (size_t)m * N + n;
                    if (ADD_RES) v += RES[idx];
                    if (F32OUT) ((float*)Cp)[idx] = v;
                    else        ((short*)Cp)[idx] = f2b(v);
                }
            }
}

// ---------------------------------------------------------------------------
// Fused depthwise causal conv(K=4)+bias+SiLU -> xc[b][l][c] AND uT[b][c][l].
// ---------------------------------------------------------------------------
__global__ __launch_bounds__(256) void conv_silu_t_kernel(
    const short* __restrict__ xi, const float* __restrict__ cw,
    const float* __restrict__ cb, short* __restrict__ xc,
    short* __restrict__ uT) {
    __shared__ short tin[67][72];
    __shared__ short tout[64][72];
    const int bb = blockIdx.z;
    const int l0 = blockIdx.x * 64;
    const int c0 = blockIdx.y * 64;
    const int tid = threadIdx.x;

    for (int idx = tid; idx < 67 * 8; idx += 256) {
        int row = idx >> 3, cs = (idx & 7) * 8;
        int ls = l0 - 3 + row;
        short8 v;
        if (ls >= 0) {
            v = *(const short8*)(xi + ((size_t)(bb * LSEQ + ls)) * DINNER + c0 + cs);
        } else {
#pragma unroll
            for (int j = 0; j < 8; ++j) v[j] = 0;
        }
        *(short8*)&tin[row][cs] = v;
    }
    __syncthreads();

    const int r    = tid >> 2;
    const int cb16 = (tid & 3) * 16;
    short8 a[4][2];
#pragma unroll
    for (int k = 0; k < 4; ++k) {
        a[k][0] = *(const short8*)&tin[r + k][cb16];
        a[k][1] = *(const short8*)&tin[r + k][cb16 + 8];
    }
    short o16[16];
#pragma unroll
    for (int j = 0; j < 16; ++j) {
        const int c = c0 + cb16 + j;
        float4 w4 = *(const float4*)(cw + (size_t)c * 4);
        float acc = cb[c];
        acc += b2f(a[0][j >> 3][j & 7]) * w4.x;
        acc += b2f(a[1][j >> 3][j & 7]) * w4.y;
        acc += b2f(a[2][j >> 3][j & 7]) * w4.z;
        acc += b2f(a[3][j >> 3][j & 7]) * w4.w;
        o16[j] = f2b(acc / (1.f + __expf(-acc)));
    }
    {
        short8 lo, hi;
#pragma unroll
        for (int j = 0; j < 8; ++j) { lo[j] = o16[j]; hi[j] = o16[8 + j]; }
        short* dst = xc + ((size_t)(bb * LSEQ + l0 + r)) * DINNER + c0 + cb16;
        *(short8*)dst = lo;
        *(short8*)(dst + 8) = hi;
    }
#pragma unroll
    for (int j = 0; j < 16; ++j) tout[r][cb16 + j] = o16[j];
    __syncthreads();

    const int rr = tid >> 3;          // 0..31
    const int l8 = (tid & 7) * 8;     // 0..56
#pragma unroll
    for (int p = 0; p < 2; ++p) {
        int cr = p * 32 + rr;
        short8 v;
#pragma unroll
        for (int j = 0; j < 8; ++j) v[j] = tout[l8 + j][cr];
        *(short8*)(uT + ((size_t)(bb * DINNER + c0 + cr)) * LSEQ + l0 + l8) = v;
    }
}

// ---------------------------------------------------------------------------
// x_proj -> transposed outputs: BT[b][n][l], CT[b][n][l], s32T[b][l].
// 2 tokens per block; per-token math bit-identical.
// ---------------------------------------------------------------------------
__global__ __launch_bounds__(256) void xproj_kernel(
    const short* __restrict__ xc, const float* __restrict__ W,
    float* __restrict__ BT, float* __restrict__ CT, float* __restrict__ s32T) {
    const int t0 = blockIdx.x * 2, tid = threadIdx.x;
    float xv0[16], xv1[16];
    {
        short8 a = *(const short8*)(xc + (size_t)t0 * DINNER + tid * 16);
        short8 b = *(const short8*)(xc + (size_t)t0 * DINNER + tid * 16 + 8);
        short8 c = *(const short8*)(xc + (size_t)(t0 + 1) * DINNER + tid * 16);
        short8 d = *(const short8*)(xc + (size_t)(t0 + 1) * DINNER + tid * 16 + 8);
#pragma unroll
        for (int j = 0; j < 8; ++j) {
            xv0[j] = b2f(a[j]); xv0[8 + j] = b2f(b[j]);
            xv1[j] = b2f(c[j]); xv1[8 + j] = b2f(d[j]);
        }
    }
    float acc0[33], acc1[33];
#pragma unroll
    for (int e = 0; e < 33; ++e) {
        const float4* wr = (const float4*)(W + (size_t)e * DINNER + tid * 16);
        float4 w0 = wr[0], w1 = wr[1], w2 = wr[2], w3 = wr[3];
        float wv[16] = {w0.x, w0.y, w0.z, w0.w, w1.x, w1.y, w1.z, w1.w,
                        w2.x, w2.y, w2.z, w2.w, w3.x, w3.y, w3.z, w3.w};
        float s0 = 0.f, s1 = 0.f;
#pragma unroll
        for (int j = 0; j < 16; ++j) { s0 += xv0[j] * wv[j]; s1 += xv1[j] * wv[j]; }
        acc0[e] = s0; acc1[e] = s1;
    }
    __shared__ float red[4][33];
#pragma unroll
    for (int tk = 0; tk < 2; ++tk) {
#pragma unroll
        for (int e = 0; e < 33; ++e) {
            float v = tk ? acc1[e] : acc0[e];
#pragma unroll
            for (int o = 32; o > 0; o >>= 1) v += __shfl_down(v, o, 64);
            if ((tid & 63) == 0) red[tid >> 6][e] = v;
        }
        __syncthreads();
        if (tid < 33) {
            float val = red[0][tid] + red[1][tid] + red[2][tid] + red[3][tid];
            const int t = t0 + tk;
            const int bb = t >> 11, l = t & (LSEQ - 1);
            if (tid < 16)
                BT[((size_t)bb * NSTATE + tid) * LSEQ + l] = val;
            else if (tid < 32)
                CT[((size_t)bb * NSTATE + (tid - 16)) * LSEQ + l] = val;
            else
                s32T[(size_t)bb * LSEQ + l] = val;
        }
        __syncthreads();
    }
}

// ---------------------------------------------------------------------------
// dt precompute: dt[b][c][l] = softplus(s32T[b][l]*dtw[c]+dtb[c]) fp32.
// ---------------------------------------------------------------------------
__global__ __launch_bounds__(256) void dt_kernel(
    const float* __restrict__ s32T, const float* __restrict__ dt_w,
    const float* __restrict__ dt_b, float* __restrict__ dtT0,
    float* __restrict__ dtT1) {
    const int chain = blockIdx.x;
    const int b = chain >> 12;
    const int c = chain & (DINNER - 1);
    const float dtw = dt_w[c], dtb = dt_b[c];
    const float* src = s32T + (size_t)b * LSEQ + threadIdx.x * 8;
    float* dst = (b ? dtT1 : dtT0) + (size_t)c * LSEQ + threadIdx.x * 8;
    float4 s0 = ((const float4*)src)[0], s1 = ((const float4*)src)[1];
    float sv[8] = {s0.x, s0.y, s0.z, s0.w, s1.x, s1.y, s1.z, s1.w};
    float dv[8];
#pragma unroll
    for (int j = 0; j < 8; ++j) {
        float v = sv[j] * dtw + dtb;
        dv[j] = (v > 20.f) ? v : __logf(1.f + __expf(v));
    }
    ((float4*)dst)[0] = make_float4(dv[0], dv[1], dv[2], dv[3]);
    ((float4*)dst)[1] = make_float4(dv[4], dv[5], dv[6], dv[7]);
}

// ---------------------------------------------------------------------------
// State-parallel selective scan, v6. TWO chains per lane (slot s handles
// chain blk*32+s and blk*32+16+s) -> intra-wave ILP fills the dependency
// stalls that phase-locked TLP could not. B/C streams are shared by both
// chains (they depend only on (b,n,l)). Per-chain op sequence, operand
// order, and reduce order (^8,^4,^2,^1) identical to v5 -> bit-identical.
// ^8 stage via DPP row_ror:8 (same data movement as swizzle-xor8).
// ---------------------------------------------------------------------------
#define GQ 4
__global__ __launch_bounds__(256) void scan_state_kernel(
    const float* __restrict__ BT, const float* __restrict__ CT,
    const float* __restrict__ dtT0, const float* __restrict__ dtT1,
    const short* __restrict__ uT, const short* __restrict__ Z,
    short* __restrict__ yout,
    const float* __restrict__ A_log, const float* __restrict__ D_par) {
    const int tid  = threadIdx.x;
    const int n    = tid & 15;
    const int slot = tid >> 4;
    const int cA   = blockIdx.x * 32 + slot;   // chain A
    const int cB   = cA + 16;                  // chain B (same batch b)
    const int b    = cA >> 12;
    const int ca   = cA & (DINNER - 1);
    const int cb2  = cB & (DINNER - 1);

    const float AnA = -__expf(A_log[ca * NSTATE + n]);
    const float AnB = -__expf(A_log[cb2 * NSTATE + n]);
    const float DpA = D_par[ca];
    const float DpB = D_par[cb2];

    const float* Bb  = BT + ((size_t)b * NSTATE + n) * LSEQ;  // shared A/B
    const float* Cb  = CT + ((size_t)b * NSTATE + n) * LSEQ;  // shared A/B
    const float* dbA = (b ? dtT1 : dtT0) + (size_t)ca * LSEQ;
    const float* dbB = (b ? dtT1 : dtT0) + (size_t)cb2 * LSEQ;
    const short* ubA = uT + (size_t)cA * LSEQ;
    const short* ubB = uT + (size_t)cB * LSEQ;
    const short* ueA = ubA + n;
    const short* ueB = ubB + n;
    const short* zpA = Z + ((size_t)b * LSEQ + n) * DINNER + ca;
    const short* zpB = Z + ((size_t)b * LSEQ + n) * DINNER + cb2;
    short*       ypA = yout + ((size_t)b * LSEQ + n) * DINNER + ca;
    short*       ypB = yout + ((size_t)b * LSEQ + n) * DINNER + cb2;

    f32x4 Bq[GQ], Cq[GQ], dqA[GQ], dqB[GQ];
    uint2 uqA[GQ], uqB[GQ];
#pragma unroll
    for (int g = 0; g < GQ; ++g) {
        Bq[g]  = *(const f32x4*)(Bb + g * 4);
        Cq[g]  = *(const f32x4*)(Cb + g * 4);
        dqA[g] = *(const f32x4*)(dbA + g * 4);
        dqB[g] = *(const f32x4*)(dbB + g * 4);
        uqA[g] = *(const uint2*)(ubA + g * 4);
        uqB[g] = *(const uint2*)(ubB + g * 4);
    }

    float hA = 0.f, hB = 0.f;
    for (int l0 = 0; l0 < LSEQ; l0 += 16) {
        const float uA = b2f(ueA[0]), zA = b2f(zpA[0]);
        const float uB = b2f(ueB[0]), zB = b2f(zpB[0]);
        const bool refill = (l0 + 16 < LSEQ);
        float ysA = 0.f, ysB = 0.f;
#pragma unroll
        for (int g = 0; g < GQ; ++g) {
            f32x4 B4 = Bq[g], C4 = Cq[g], dA4 = dqA[g], dB4 = dqB[g];
            uint2 u4A = uqA[g], u4B = uqB[g];
            if (refill) {
                const int lp = l0 + 16 + g * 4;   // lp+3 <= 2047: in-bounds
                Bq[g]  = *(const f32x4*)(Bb + lp);
                Cq[g]  = *(const f32x4*)(Cb + lp);
                dqA[g] = *(const f32x4*)(dbA + lp);
                dqB[g] = *(const f32x4*)(dbB + lp);
                uqA[g] = *(const uint2*)(ubA + lp);
                uqB[g] = *(const uint2*)(ubB + lp);
            }
            float uvA[4], uvB[4], eA[4], eB[4];
#pragma unroll
            for (int i = 0; i < 4; ++i) {
                unsigned wA = (i < 2) ? u4A.x : u4A.y;
                unsigned wB = (i < 2) ? u4B.x : u4B.y;
                union { unsigned uu; float ff; } t0, t1;
                t0.uu = (i & 1) ? (wA & 0xffff0000u) : (wA << 16);
                t1.uu = (i & 1) ? (wB & 0xffff0000u) : (wB << 16);
                uvA[i] = t0.ff; uvB[i] = t1.ff;
                eA[i] = __expf(dA4[i] * AnA);
                eB[i] = __expf(dB4[i] * AnB);
            }
            float pA[4], pB[4];
#pragma unroll
            for (int i = 0; i < 4; ++i) {
                hA = eA[i] * hA + (dA4[i] * uvA[i]) * B4[i];
                pA[i] = hA * C4[i];
            }
#pragma unroll
            for (int i = 0; i < 4; ++i) {
                hB = eB[i] * hB + (dB4[i] * uvB[i]) * B4[i];
                pB[i] = hB * C4[i];
            }
            float tA[4], tB[4];
#pragma unroll
            for (int i = 0; i < 4; ++i) { tA[i] = ror8(pA[i]); tB[i] = ror8(pB[i]); }
#pragma unroll
            for (int i = 0; i < 4; ++i) { pA[i] += tA[i]; pB[i] += tB[i]; }
#pragma unroll
            for (int i = 0; i < 4; ++i) { tA[i] = swz<0x101F>(pA[i]); tB[i] = swz<0x101F>(pB[i]); }
#pragma unroll
            for (int i = 0; i < 4; ++i) { pA[i] += tA[i]; pB[i] += tB[i]; }
#pragma unroll
            for (int i = 0; i < 4; ++i) { pA[i] += qperm<0x4E>(pA[i]); pB[i] += qperm<0x4E>(pB[i]); }
#pragma unroll
            for (int i = 0; i < 4; ++i) { pA[i] += qperm<0xB1>(pA[i]); pB[i] += qperm<0xB1>(pB[i]); }
#pragma unroll
            for (int i = 0; i < 4; ++i) {
                ysA = (n == g * 4 + i) ? pA[i] : ysA;
                ysB = (n == g * 4 + i) ? pB[i] : ysB;
            }
        }
        {
            float yA  = ysA + DpA * uA;
            float zgA = zA / (1.f + __expf(-zA));
            ypA[0] = f2b(yA * zgA);
            float yB  = ysB + DpB * uB;
            float zgB = zB / (1.f + __expf(-zB));
            ypB[0] = f2b(yB * zgB);
        }
        ueA += 16; ueB += 16;
        zpA += (size_t)16 * DINNER; zpB += (size_t)16 * DINNER;
        ypA += (size_t)16 * DINNER; ypB += (size_t)16 * DINNER;
    }
}

// ---------------------------------------------------------------------------
extern "C" void kernel_launch(void* const* d_in, const int* in_sizes, int n_in,
                              void* d_out, int out_size, void* d_ws, size_t ws_size,
                              hipStream_t stream) {
    const float* x      = (const float*)d_in[0];
    const float* norm_w = (const float*)d_in[1];
    const float* w_in   = (const float*)d_in[2];   // (8192, 2048)
    const float* conv_w = (const float*)d_in[3];
    const float* conv_b = (const float*)d_in[4];
    const float* w_xp   = (const float*)d_in[5];   // (33, 4096)
    const float* dt_w   = (const float*)d_in[6];
    const float* dt_b   = (const float*)d_in[7];
    const float* A_log  = (const float*)d_in[8];
    const float* D_par  = (const float*)d_in[9];
    const float* w_out  = (const float*)d_in[10];  // (2048, 4096)
    float* out = (float*)d_out;

    char* ws = (char*)d_ws;
    short* wb   = (short*)(ws);                        // 32 MB: w_in bf16; after GEMM1: uT
    short* xn   = (short*)(ws + (size_t)(32 << 20));   // 16 MB: xn; later w_out bf16
    short* Xi   = (short*)(ws + (size_t)(48 << 20));   // 32 MB: x_inner; later dtT0 (fp32)
    short* Zb   = (short*)(ws + (size_t)(80 << 20));   // 32 MB: z half
    short* xc   = (short*)(ws + (size_t)(112 << 20));  // 32 MB: u; y written in place
    float* BT   = (float*)(ws + (size_t)(144 << 20));               // 256 KB
    float* CT   = (float*)(ws + (size_t)(144 << 20) + (256 << 10)); // 256 KB
    float* s32T = (float*)(ws + (size_t)(144 << 20) + (512 << 10)); // 16 KB
    float* dtT0 = (float*)Xi;     // b=0 half of dt (32 MB, Xi dead after conv)
    float* dtT1 = out;            // b=1 half of dt (d_out dead until final GEMM)

    // 1. w_in -> bf16
    f32_to_bf16_kernel<<<(2 * DINNER * DMODEL / 8) / 256, 256, 0, stream>>>(
        w_in, wb, 2 * DINNER * DMODEL / 8);
    // 2. RMSNorm
    rmsnorm_kernel<<<NTOK, 256, 0, stream>>>(x, norm_w, xn);
    // 3. in_proj GEMM -> split Xi / Zb (bf16)
    gemm_bt<false, false, true><<<dim3(NTOK / 128, 8192 / 128), 256, 0, stream>>>(
        xn, wb, nullptr, Xi, Zb, NTOK, 2 * DINNER, DMODEL);
    // 4. fused conv + SiLU + transpose -> xc (row-major) and uT (into wb)
    conv_silu_t_kernel<<<dim3(LSEQ / 64, DINNER / 64, 2), 256, 0, stream>>>(
        Xi, conv_w, conv_b, xc, wb);
    // 5. x_proj -> BT/CT/s32T (transposed), 2 tokens/block
    xproj_kernel<<<NTOK / 2, 256, 0, stream>>>(xc, w_xp, BT, CT, s32T);
    // 5c. dt precompute (Xi dead after conv; out dead until step 8)
    dt_kernel<<<NCHAIN, 256, 0, stream>>>(s32T, dt_w, dt_b, dtT0, dtT1);
    // 6. selective scan, 2 chains/lane (gated y written into xc)
    scan_state_kernel<<<NCHAIN / 32, 256, 0, stream>>>(
        BT, CT, dtT0, dtT1, wb, Zb, xc, A_log, D_par);
    // 7. w_out -> bf16 into xn region
    f32_to_bf16_kernel<<<(DMODEL * DINNER / 8) / 256, 256, 0, stream>>>(
        w_out, xn, DMODEL * DINNER / 8);
    // 8. out_proj GEMM + residual -> fp32 out (overwrites dtT1 scratch)
    gemm_bt<true, true, false><<<dim3(NTOK / 128, DMODEL / 128), 256, 0, stream>>>(
        xc, xn, x, out, nullptr, NTOK, DMODEL, DINNER);
}

// Round 7
// 955.535 us; speedup vs baseline: 1.6893x; 1.0632x over previous
//
#include <hip/hip_runtime.h>

#define NTOK   4096   // BATCH * L
#define LSEQ   2048
#define DMODEL 2048
#define DINNER 4096
#define NSTATE 16
#define NCHAIN 8192   // BATCH * DINNER

using short8 = __attribute__((ext_vector_type(8))) short;
using f32x4  = __attribute__((ext_vector_type(4))) float;

__device__ inline float b2f(short s) {
    union { unsigned u; float f; } v;
    v.u = ((unsigned)(unsigned short)s) << 16;
    return v.f;
}
__device__ inline short f2b(float f) {
    unsigned u = __float_as_uint(f);
    unsigned r = (u + 0x7fffu + ((u >> 16) & 1u)) >> 16;
    return (short)r;
}

// lane^4 via ds_swizzle BitMode (identical movement to shfl_xor w16 stage)
template <int OFF>
__device__ inline float swz(float v) {
    return __int_as_float(__builtin_amdgcn_ds_swizzle(__float_as_int(v), OFF));
}
// lane^2 / lane^1 via quad_perm DPP (VALU latency, no LDS)
template <int CTRL>
__device__ inline float qperm(float v) {
    return __int_as_float(
        __builtin_amdgcn_mov_dpp(__float_as_int(v), CTRL, 0xF, 0xF, true));
}
// lane^8 within 16-lane row via DPP row_ror:8 ((i+8)&15 == i^8)
__device__ inline float ror8(float v) {
    return __int_as_float(
        __builtin_amdgcn_mov_dpp(__float_as_int(v), 0x128, 0xF, 0xF, true));
}

// ---------------------------------------------------------------------------
// fp32 -> bf16 bulk convert (8 elems/thread)
// ---------------------------------------------------------------------------
__global__ __launch_bounds__(256) void f32_to_bf16_kernel(
    const float* __restrict__ in, short* __restrict__ out, int n8) {
    int i = blockIdx.x * 256 + threadIdx.x;
    if (i >= n8) return;
    const float4* p = (const float4*)in + 2 * (size_t)i;
    float4 a = p[0], b = p[1];
    short8 s;
    s[0] = f2b(a.x); s[1] = f2b(a.y); s[2] = f2b(a.z); s[3] = f2b(a.w);
    s[4] = f2b(b.x); s[5] = f2b(b.y); s[6] = f2b(b.z); s[7] = f2b(b.w);
    *(short8*)(out + 8 * (size_t)i) = s;
}

// ---------------------------------------------------------------------------
// RMSNorm: x (NTOK x DMODEL fp32) -> xn bf16
// ---------------------------------------------------------------------------
__global__ __launch_bounds__(256) void rmsnorm_kernel(
    const float* __restrict__ x, const float* __restrict__ w,
    short* __restrict__ xn) {
    const int t = blockIdx.x, tid = threadIdx.x;
    const float4* xr = (const float4*)(x + (size_t)t * DMODEL + tid * 8);
    float4 a = xr[0], b = xr[1];
    float v[8] = {a.x, a.y, a.z, a.w, b.x, b.y, b.z, b.w};
    float ss = 0.f;
#pragma unroll
    for (int j = 0; j < 8; ++j) ss += v[j] * v[j];
#pragma unroll
    for (int o = 32; o > 0; o >>= 1) ss += __shfl_down(ss, o, 64);
    __shared__ float sred[4];
    if ((tid & 63) == 0) sred[tid >> 6] = ss;
    __syncthreads();
    float r = rsqrtf((sred[0] + sred[1] + sred[2] + sred[3]) * (1.f / DMODEL) + 1e-5f);
    const float4* wr = (const float4*)(w + tid * 8);
    float4 wa = wr[0], wb = wr[1];
    float wv[8] = {wa.x, wa.y, wa.z, wa.w, wb.x, wb.y, wb.z, wb.w};
    short8 o8;
#pragma unroll
    for (int j = 0; j < 8; ++j) o8[j] = f2b(v[j] * r * wv[j]);
    *(short8*)(xn + (size_t)t * DMODEL + tid * 8) = o8;
}

// ---------------------------------------------------------------------------
// 8-phase 256x256 GEMM (bf16 in, fp32 accum), C = A[M,K] * B[N,K]^T.
// Split bf16 output (n<DINNER -> Cp, else Cp2), row stride DINNER.
// Schedule: 2 K-tiles (BK=64) per iteration, 8 phases; per phase:
// {ds_read subtile | stage 1 half-tile (2 gload_lds) | setprio+16 MFMA |
//  [vmcnt(2) at phases 4,8] | s_barrier}. LDS XOR-swizzle byte^=(row&7)<<4
// applied on BOTH sides: pre-swizzled gload_lds SOURCE + swizzled ds_read.
// Buffer hazards (verified phase-by-phase):
//   buf0 A reads issued P0(LDA qm0)/P2(LDA qm1), done at P2-end barrier ->
//     P3..P6 stage tile 2t+2 into buf0. buf0/1 B reads done by P1/P5-end.
//   buf1 reads P4..P6, done at P7-end barrier -> P7,P0-P2 stage tile 2t+3.
//   vmcnt(2) at end-P3: 10 outstanding, oldest 8 = tile 2t+1 -> drained.
//   vmcnt(2) at end-P7: 10 outstanding, oldest 8 = tile 2t+2 -> drained.
//   last iter: end-P3 uses vmcnt(0) (only 8 outstanding, all needed).
// Control flow is wave-uniform everywhere (no divergent barriers).
// ---------------------------------------------------------------------------
__global__ __launch_bounds__(512, 2) void gemm8_split(
    const short* __restrict__ A, const short* __restrict__ B,
    short* __restrict__ Cp, short* __restrict__ Cp2, int K) {
    __shared__ __align__(16) short Alds[2][256][64];   // 64 KiB
    __shared__ __align__(16) short Blds[2][256][64];   // 64 KiB

    const int tid = threadIdx.x;
    const int lane = tid & 63;
    const int lr = lane & 15;
    const int q2 = lane >> 4;
    const int w  = tid >> 6;
    const int wmp = w >> 2;      // 0..1 (M)
    const int wnp = w & 3;       // 0..3 (N)
    const int m0 = blockIdx.x * 256;
    const int n0 = blockIdx.y * 256;
    const int NT = K / 64;
    const int niter = NT / 2;

    f32x4 acc[8][4] = {};
    short8 Af[4][2];
    short8 Bf[4][2];

    // stage one half-tile (2 gload_lds): chunk c of tile T
    // c=0,1 : A halves ; c=2,3 : B halves
    auto STAGE = [&](int T, int c) {
        if (T >= NT) return;
        const int buf = T & 1;
        const int k0 = T * 64;
        const bool isA = (c < 2);
        const int half = c & 1;
        const short* G = isA ? A : B;
        const int row0 = isA ? m0 : n0;
        char* ldsbase = isA ? (char*)&Alds[buf][0][0] : (char*)&Blds[buf][0][0];
#pragma unroll
        for (int j = 0; j < 2; ++j) {
            int r = half * 128 + j * 64 + (tid >> 3);
            int csrc = ((tid & 7) * 8) ^ ((r & 7) * 8);
            const short* src = G + (size_t)(row0 + r) * K + k0 + csrc;
            __builtin_amdgcn_global_load_lds(
                (const __attribute__((address_space(1))) void*)src,
                (__attribute__((address_space(3))) void*)(
                    ldsbase + half * 16384 + j * 8192 + tid * 16),
                16, 0, 0);
        }
    };
    auto LDA = [&](int buf, int qm) {
#pragma unroll
        for (int mf2 = 0; mf2 < 4; ++mf2)
#pragma unroll
            for (int ks = 0; ks < 2; ++ks) {
                int r = wmp * 128 + qm * 64 + mf2 * 16 + lr;
                int ce = (ks * 32 + q2 * 8) ^ ((lr & 7) << 3);
                Af[mf2][ks] = *(const short8*)&Alds[buf][r][ce];
            }
    };
    auto LDB = [&](int buf, int qn) {
#pragma unroll
        for (int nf2 = 0; nf2 < 2; ++nf2)
#pragma unroll
            for (int ks = 0; ks < 2; ++ks) {
                int r = wnp * 64 + qn * 32 + nf2 * 16 + lr;
                int ce = (ks * 32 + q2 * 8) ^ ((lr & 7) << 3);
                Bf[qn * 2 + nf2][ks] = *(const short8*)&Blds[buf][r][ce];
            }
    };
    auto MM = [&](int qm, int qn) {
        __builtin_amdgcn_s_setprio(1);
#pragma unroll
        for (int mf2 = 0; mf2 < 4; ++mf2)
#pragma unroll
            for (int nf2 = 0; nf2 < 2; ++nf2)
#pragma unroll
                for (int ks = 0; ks < 2; ++ks)
                    acc[qm * 4 + mf2][qn * 2 + nf2] =
                        __builtin_amdgcn_mfma_f32_16x16x32_bf16(
                            Af[mf2][ks], Bf[qn * 2 + nf2][ks],
                            acc[qm * 4 + mf2][qn * 2 + nf2], 0, 0, 0);
        __builtin_amdgcn_s_setprio(0);
    };

    // prologue: tiles 0 and 1 fully staged; wait tile0 (leave tile1's 8 in flight)
#pragma unroll
    for (int c = 0; c < 4; ++c) STAGE(0, c);
#pragma unroll
    for (int c = 0; c < 4; ++c) STAGE(1, c);
    asm volatile("s_waitcnt vmcnt(8)" ::: "memory");
    __builtin_amdgcn_sched_barrier(0);
    __builtin_amdgcn_s_barrier();

    for (int t = 0; t < niter; ++t) {
        const int T0 = 2 * t;
        // P0
        LDA(0, 0); LDB(0, 0);
        if (t > 0) STAGE(T0 + 1, 1);
        MM(0, 0);
        __builtin_amdgcn_s_barrier();
        // P1
        LDB(0, 1);
        if (t > 0) STAGE(T0 + 1, 2);
        MM(0, 1);
        __builtin_amdgcn_s_barrier();
        // P2
        LDA(0, 1);
        if (t > 0) STAGE(T0 + 1, 3);
        MM(1, 0);
        __builtin_amdgcn_s_barrier();
        // P3
        STAGE(T0 + 2, 0);
        MM(1, 1);
        if (t + 1 < niter) {
            asm volatile("s_waitcnt vmcnt(2)" ::: "memory");
        } else {
            asm volatile("s_waitcnt vmcnt(0)" ::: "memory");
        }
        __builtin_amdgcn_sched_barrier(0);
        __builtin_amdgcn_s_barrier();
        // P4
        LDA(1, 0); LDB(1, 0);
        STAGE(T0 + 2, 1);
        MM(0, 0);
        __builtin_amdgcn_s_barrier();
        // P5
        LDB(1, 1);
        STAGE(T0 + 2, 2);
        MM(0, 1);
        __builtin_amdgcn_s_barrier();
        // P6
        LDA(1, 1);
        STAGE(T0 + 2, 3);
        MM(1, 0);
        __builtin_amdgcn_s_barrier();
        // P7
        STAGE(T0 + 3, 0);
        MM(1, 1);
        if (t + 1 < niter) {
            asm volatile("s_waitcnt vmcnt(2)" ::: "memory");
            __builtin_amdgcn_sched_barrier(0);
            __builtin_amdgcn_s_barrier();
        }
    }

    // epilogue: split bf16 write (whole block lies in one half)
    const bool hi = (n0 >= DINNER);
    short* sdst = hi ? Cp2 : Cp;
    const int noff = hi ? DINNER : 0;
#pragma unroll
    for (int mf = 0; mf < 8; ++mf)
#pragma unroll
        for (int nf = 0; nf < 4; ++nf)
#pragma unroll
            for (int rr2 = 0; rr2 < 4; ++rr2) {
                int m = m0 + wmp * 128 + mf * 16 + q2 * 4 + rr2;
                int n = n0 + wnp * 64 + nf * 16 + lr;
                sdst[(size_t)m * DINNER + (n - noff)] = f2b(acc[mf][nf][rr2]);
            }
}

// ---------------------------------------------------------------------------
// GEMM C[M,N] = A[M,K] * B[N,K]^T  (bf16 in, fp32 accum), m97 structure.
// Used for out_proj (N=2048: 256^2 grid would idle half the CUs).
// ---------------------------------------------------------------------------
template <bool ADD_RES, bool F32OUT>
__global__ __launch_bounds__(256) void gemm_bt(
    const short* __restrict__ A, const short* __restrict__ B,
    const float* __restrict__ RES, void* __restrict__ Cp,
    int M, int N, int K) {
    __shared__ __align__(16) short As[128 * 32];
    __shared__ __align__(16) short Bs[128 * 32];

    const int tid  = threadIdx.x;
    const int wave = tid >> 6;
    const int lane = tid & 63;
    const int lr   = lane & 15;
    const int q    = lane >> 4;
    const int m0   = blockIdx.x * 128;
    const int n0   = blockIdx.y * 128;
    const int wm   = (wave >> 1) * 64;
    const int wn   = (wave & 1) * 64;

    f32x4 acc[4][4] = {};

    for (int k0 = 0; k0 < K; k0 += 32) {
#pragma unroll
        for (int p = 0; p < 2; ++p) {
            int i16 = p * 256 + tid;
            int row = i16 >> 2, ch = i16 & 3;
            const short* ga = A + (size_t)(m0 + row) * K + k0 + ch * 8;
            const short* gb = B + (size_t)(n0 + row) * K + k0 + ch * 8;
            __builtin_amdgcn_global_load_lds(
                (const __attribute__((address_space(1))) void*)ga,
                (__attribute__((address_space(3))) void*)((char*)As + i16 * 16),
                16, 0, 0);
            __builtin_amdgcn_global_load_lds(
                (const __attribute__((address_space(1))) void*)gb,
                (__attribute__((address_space(3))) void*)((char*)Bs + i16 * 16),
                16, 0, 0);
        }
        __syncthreads();

        short8 af[4], bfr[4];
#pragma unroll
        for (int i = 0; i < 4; ++i) {
            af[i]  = *(const short8*)&As[(wm + i * 16 + lr) * 32 + q * 8];
            bfr[i] = *(const short8*)&Bs[(wn + i * 16 + lr) * 32 + q * 8];
        }
#pragma unroll
        for (int i = 0; i < 4; ++i)
#pragma unroll
            for (int j = 0; j < 4; ++j)
                acc[i][j] = __builtin_amdgcn_mfma_f32_16x16x32_bf16(
                    af[i], bfr[j], acc[i][j], 0, 0, 0);
        __syncthreads();
    }

#pragma unroll
    for (int i = 0; i < 4; ++i)
#pragma unroll
        for (int j = 0; j < 4; ++j)
#pragma unroll
            for (int r = 0; r < 4; ++r) {
                int m = m0 + wm + i * 16 + q * 4 + r;
                int n = n0 + wn + j * 16 + lr;
                size_t idx = (size_t)m * N + n;
                float v = acc[i][j][r];
                if (ADD_RES) v += RES[idx];
                if (F32OUT) ((float*)Cp)[idx] = v;
                else        ((short*)Cp)[idx] = f2b(v);
            }
}

// ---------------------------------------------------------------------------
// Fused depthwise causal conv(K=4)+bias+SiLU -> xc[b][l][c] AND uT[b][c][l].
// ---------------------------------------------------------------------------
__global__ __launch_bounds__(256) void conv_silu_t_kernel(
    const short* __restrict__ xi, const float* __restrict__ cw,
    const float* __restrict__ cb, short* __restrict__ xc,
    short* __restrict__ uT) {
    __shared__ short tin[67][72];
    __shared__ short tout[64][72];
    const int bb = blockIdx.z;
    const int l0 = blockIdx.x * 64;
    const int c0 = blockIdx.y * 64;
    const int tid = threadIdx.x;

    for (int idx = tid; idx < 67 * 8; idx += 256) {
        int row = idx >> 3, cs = (idx & 7) * 8;
        int ls = l0 - 3 + row;
        short8 v;
        if (ls >= 0) {
            v = *(const short8*)(xi + ((size_t)(bb * LSEQ + ls)) * DINNER + c0 + cs);
        } else {
#pragma unroll
            for (int j = 0; j < 8; ++j) v[j] = 0;
        }
        *(short8*)&tin[row][cs] = v;
    }
    __syncthreads();

    const int r    = tid >> 2;
    const int cb16 = (tid & 3) * 16;
    short8 a[4][2];
#pragma unroll
    for (int k = 0; k < 4; ++k) {
        a[k][0] = *(const short8*)&tin[r + k][cb16];
        a[k][1] = *(const short8*)&tin[r + k][cb16 + 8];
    }
    short o16[16];
#pragma unroll
    for (int j = 0; j < 16; ++j) {
        const int c = c0 + cb16 + j;
        float4 w4 = *(const float4*)(cw + (size_t)c * 4);
        float acc = cb[c];
        acc += b2f(a[0][j >> 3][j & 7]) * w4.x;
        acc += b2f(a[1][j >> 3][j & 7]) * w4.y;
        acc += b2f(a[2][j >> 3][j & 7]) * w4.z;
        acc += b2f(a[3][j >> 3][j & 7]) * w4.w;
        o16[j] = f2b(acc / (1.f + __expf(-acc)));
    }
    {
        short8 lo, hi;
#pragma unroll
        for (int j = 0; j < 8; ++j) { lo[j] = o16[j]; hi[j] = o16[8 + j]; }
        short* dst = xc + ((size_t)(bb * LSEQ + l0 + r)) * DINNER + c0 + cb16;
        *(short8*)dst = lo;
        *(short8*)(dst + 8) = hi;
    }
#pragma unroll
    for (int j = 0; j < 16; ++j) tout[r][cb16 + j] = o16[j];
    __syncthreads();

    const int rr = tid >> 3;          // 0..31
    const int l8 = (tid & 7) * 8;     // 0..56
#pragma unroll
    for (int p = 0; p < 2; ++p) {
        int cr = p * 32 + rr;
        short8 v;
#pragma unroll
        for (int j = 0; j < 8; ++j) v[j] = tout[l8 + j][cr];
        *(short8*)(uT + ((size_t)(bb * DINNER + c0 + cr)) * LSEQ + l0 + l8) = v;
    }
}

// ---------------------------------------------------------------------------
// x_proj -> transposed outputs: BT[b][n][l], CT[b][n][l], s32T[b][l].
// 2 tokens per block; per-token math bit-identical.
// ---------------------------------------------------------------------------
__global__ __launch_bounds__(256) void xproj_kernel(
    const short* __restrict__ xc, const float* __restrict__ W,
    float* __restrict__ BT, float* __restrict__ CT, float* __restrict__ s32T) {
    const int t0 = blockIdx.x * 2, tid = threadIdx.x;
    float xv0[16], xv1[16];
    {
        short8 a = *(const short8*)(xc + (size_t)t0 * DINNER + tid * 16);
        short8 b = *(const short8*)(xc + (size_t)t0 * DINNER + tid * 16 + 8);
        short8 c = *(const short8*)(xc + (size_t)(t0 + 1) * DINNER + tid * 16);
        short8 d = *(const short8*)(xc + (size_t)(t0 + 1) * DINNER + tid * 16 + 8);
#pragma unroll
        for (int j = 0; j < 8; ++j) {
            xv0[j] = b2f(a[j]); xv0[8 + j] = b2f(b[j]);
            xv1[j] = b2f(c[j]); xv1[8 + j] = b2f(d[j]);
        }
    }
    float acc0[33], acc1[33];
#pragma unroll
    for (int e = 0; e < 33; ++e) {
        const float4* wr = (const float4*)(W + (size_t)e * DINNER + tid * 16);
        float4 w0 = wr[0], w1 = wr[1], w2 = wr[2], w3 = wr[3];
        float wv[16] = {w0.x, w0.y, w0.z, w0.w, w1.x, w1.y, w1.z, w1.w,
                        w2.x, w2.y, w2.z, w2.w, w3.x, w3.y, w3.z, w3.w};
        float s0 = 0.f, s1 = 0.f;
#pragma unroll
        for (int j = 0; j < 16; ++j) { s0 += xv0[j] * wv[j]; s1 += xv1[j] * wv[j]; }
        acc0[e] = s0; acc1[e] = s1;
    }
    __shared__ float red[4][33];
#pragma unroll
    for (int tk = 0; tk < 2; ++tk) {
#pragma unroll
        for (int e = 0; e < 33; ++e) {
            float v = tk ? acc1[e] : acc0[e];
#pragma unroll
            for (int o = 32; o > 0; o >>= 1) v += __shfl_down(v, o, 64);
            if ((tid & 63) == 0) red[tid >> 6][e] = v;
        }
        __syncthreads();
        if (tid < 33) {
            float val = red[0][tid] + red[1][tid] + red[2][tid] + red[3][tid];
            const int t = t0 + tk;
            const int bb = t >> 11, l = t & (LSEQ - 1);
            if (tid < 16)
                BT[((size_t)bb * NSTATE + tid) * LSEQ + l] = val;
            else if (tid < 32)
                CT[((size_t)bb * NSTATE + (tid - 16)) * LSEQ + l] = val;
            else
                s32T[(size_t)bb * LSEQ + l] = val;
        }
        __syncthreads();
    }
}

// ---------------------------------------------------------------------------
// dt precompute: dt[b][c][l] = softplus(s32T[b][l]*dtw[c]+dtb[c]) fp32.
// ---------------------------------------------------------------------------
__global__ __launch_bounds__(256) void dt_kernel(
    const float* __restrict__ s32T, const float* __restrict__ dt_w,
    const float* __restrict__ dt_b, float* __restrict__ dtT0,
    float* __restrict__ dtT1) {
    const int chain = blockIdx.x;
    const int b = chain >> 12;
    const int c = chain & (DINNER - 1);
    const float dtw = dt_w[c], dtb = dt_b[c];
    const float* src = s32T + (size_t)b * LSEQ + threadIdx.x * 8;
    float* dst = (b ? dtT1 : dtT0) + (size_t)c * LSEQ + threadIdx.x * 8;
    float4 s0 = ((const float4*)src)[0], s1 = ((const float4*)src)[1];
    float sv[8] = {s0.x, s0.y, s0.z, s0.w, s1.x, s1.y, s1.z, s1.w};
    float dv[8];
#pragma unroll
    for (int j = 0; j < 8; ++j) {
        float v = sv[j] * dtw + dtb;
        dv[j] = (v > 20.f) ? v : __logf(1.f + __expf(v));
    }
    ((float4*)dst)[0] = make_float4(dv[0], dv[1], dv[2], dv[3]);
    ((float4*)dst)[1] = make_float4(dv[4], dv[5], dv[6], dv[7]);
}

// ---------------------------------------------------------------------------
// State-parallel selective scan, v6 (unchanged).
// ---------------------------------------------------------------------------
#define GQ 4
__global__ __launch_bounds__(256) void scan_state_kernel(
    const float* __restrict__ BT, const float* __restrict__ CT,
    const float* __restrict__ dtT0, const float* __restrict__ dtT1,
    const short* __restrict__ uT, const short* __restrict__ Z,
    short* __restrict__ yout,
    const float* __restrict__ A_log, const float* __restrict__ D_par) {
    const int tid  = threadIdx.x;
    const int n    = tid & 15;
    const int slot = tid >> 4;
    const int cA   = blockIdx.x * 32 + slot;   // chain A
    const int cB   = cA + 16;                  // chain B (same batch b)
    const int b    = cA >> 12;
    const int ca   = cA & (DINNER - 1);
    const int cb2  = cB & (DINNER - 1);

    const float AnA = -__expf(A_log[ca * NSTATE + n]);
    const float AnB = -__expf(A_log[cb2 * NSTATE + n]);
    const float DpA = D_par[ca];
    const float DpB = D_par[cb2];

    const float* Bb  = BT + ((size_t)b * NSTATE + n) * LSEQ;  // shared A/B
    const float* Cb  = CT + ((size_t)b * NSTATE + n) * LSEQ;  // shared A/B
    const float* dbA = (b ? dtT1 : dtT0) + (size_t)ca * LSEQ;
    const float* dbB = (b ? dtT1 : dtT0) + (size_t)cb2 * LSEQ;
    const short* ubA = uT + (size_t)cA * LSEQ;
    const short* ubB = uT + (size_t)cB * LSEQ;
    const short* ueA = ubA + n;
    const short* ueB = ubB + n;
    const short* zpA = Z + ((size_t)b * LSEQ + n) * DINNER + ca;
    const short* zpB = Z + ((size_t)b * LSEQ + n) * DINNER + cb2;
    short*       ypA = yout + ((size_t)b * LSEQ + n) * DINNER + ca;
    short*       ypB = yout + ((size_t)b * LSEQ + n) * DINNER + cb2;

    f32x4 Bq[GQ], Cq[GQ], dqA[GQ], dqB[GQ];
    uint2 uqA[GQ], uqB[GQ];
#pragma unroll
    for (int g = 0; g < GQ; ++g) {
        Bq[g]  = *(const f32x4*)(Bb + g * 4);
        Cq[g]  = *(const f32x4*)(Cb + g * 4);
        dqA[g] = *(const f32x4*)(dbA + g * 4);
        dqB[g] = *(const f32x4*)(dbB + g * 4);
        uqA[g] = *(const uint2*)(ubA + g * 4);
        uqB[g] = *(const uint2*)(ubB + g * 4);
    }

    float hA = 0.f, hB = 0.f;
    for (int l0 = 0; l0 < LSEQ; l0 += 16) {
        const float uA = b2f(ueA[0]), zA = b2f(zpA[0]);
        const float uB = b2f(ueB[0]), zB = b2f(zpB[0]);
        const bool refill = (l0 + 16 < LSEQ);
        float ysA = 0.f, ysB = 0.f;
#pragma unroll
        for (int g = 0; g < GQ; ++g) {
            f32x4 B4 = Bq[g], C4 = Cq[g], dA4 = dqA[g], dB4 = dqB[g];
            uint2 u4A = uqA[g], u4B = uqB[g];
            if (refill) {
                const int lp = l0 + 16 + g * 4;   // lp+3 <= 2047: in-bounds
                Bq[g]  = *(const f32x4*)(Bb + lp);
                Cq[g]  = *(const f32x4*)(Cb + lp);
                dqA[g] = *(const f32x4*)(dbA + lp);
                dqB[g] = *(const f32x4*)(dbB + lp);
                uqA[g] = *(const uint2*)(ubA + lp);
                uqB[g] = *(const uint2*)(ubB + lp);
            }
            float uvA[4], uvB[4], eA[4], eB[4];
#pragma unroll
            for (int i = 0; i < 4; ++i) {
                unsigned wA = (i < 2) ? u4A.x : u4A.y;
                unsigned wB = (i < 2) ? u4B.x : u4B.y;
                union { unsigned uu; float ff; } t0, t1;
                t0.uu = (i & 1) ? (wA & 0xffff0000u) : (wA << 16);
                t1.uu = (i & 1) ? (wB & 0xffff0000u) : (wB << 16);
                uvA[i] = t0.ff; uvB[i] = t1.ff;
                eA[i] = __expf(dA4[i] * AnA);
                eB[i] = __expf(dB4[i] * AnB);
            }
            float pA[4], pB[4];
#pragma unroll
            for (int i = 0; i < 4; ++i) {
                hA = eA[i] * hA + (dA4[i] * uvA[i]) * B4[i];
                pA[i] = hA * C4[i];
            }
#pragma unroll
            for (int i = 0; i < 4; ++i) {
                hB = eB[i] * hB + (dB4[i] * uvB[i]) * B4[i];
                pB[i] = hB * C4[i];
            }
            float tA[4], tB[4];
#pragma unroll
            for (int i = 0; i < 4; ++i) { tA[i] = ror8(pA[i]); tB[i] = ror8(pB[i]); }
#pragma unroll
            for (int i = 0; i < 4; ++i) { pA[i] += tA[i]; pB[i] += tB[i]; }
#pragma unroll
            for (int i = 0; i < 4; ++i) { tA[i] = swz<0x101F>(pA[i]); tB[i] = swz<0x101F>(pB[i]); }
#pragma unroll
            for (int i = 0; i < 4; ++i) { pA[i] += tA[i]; pB[i] += tB[i]; }
#pragma unroll
            for (int i = 0; i < 4; ++i) { pA[i] += qperm<0x4E>(pA[i]); pB[i] += qperm<0x4E>(pB[i]); }
#pragma unroll
            for (int i = 0; i < 4; ++i) { pA[i] += qperm<0xB1>(pA[i]); pB[i] += qperm<0xB1>(pB[i]); }
#pragma unroll
            for (int i = 0; i < 4; ++i) {
                ysA = (n == g * 4 + i) ? pA[i] : ysA;
                ysB = (n == g * 4 + i) ? pB[i] : ysB;
            }
        }
        {
            float yA  = ysA + DpA * uA;
            float zgA = zA / (1.f + __expf(-zA));
            ypA[0] = f2b(yA * zgA);
            float yB  = ysB + DpB * uB;
            float zgB = zB / (1.f + __expf(-zB));
            ypB[0] = f2b(yB * zgB);
        }
        ueA += 16; ueB += 16;
        zpA += (size_t)16 * DINNER; zpB += (size_t)16 * DINNER;
        ypA += (size_t)16 * DINNER; ypB += (size_t)16 * DINNER;
    }
}

// ---------------------------------------------------------------------------
extern "C" void kernel_launch(void* const* d_in, const int* in_sizes, int n_in,
                              void* d_out, int out_size, void* d_ws, size_t ws_size,
                              hipStream_t stream) {
    const float* x      = (const float*)d_in[0];
    const float* norm_w = (const float*)d_in[1];
    const float* w_in   = (const float*)d_in[2];   // (8192, 2048)
    const float* conv_w = (const float*)d_in[3];
    const float* conv_b = (const float*)d_in[4];
    const float* w_xp   = (const float*)d_in[5];   // (33, 4096)
    const float* dt_w   = (const float*)d_in[6];
    const float* dt_b   = (const float*)d_in[7];
    const float* A_log  = (const float*)d_in[8];
    const float* D_par  = (const float*)d_in[9];
    const float* w_out  = (const float*)d_in[10];  // (2048, 4096)
    float* out = (float*)d_out;

    char* ws = (char*)d_ws;
    short* wb   = (short*)(ws);                        // 32 MB: w_in bf16; after GEMM1: uT
    short* xn   = (short*)(ws + (size_t)(32 << 20));   // 16 MB: xn; later w_out bf16
    short* Xi   = (short*)(ws + (size_t)(48 << 20));   // 32 MB: x_inner; later dtT0 (fp32)
    short* Zb   = (short*)(ws + (size_t)(80 << 20));   // 32 MB: z half
    short* xc   = (short*)(ws + (size_t)(112 << 20));  // 32 MB: u; y written in place
    float* BT   = (float*)(ws + (size_t)(144 << 20));               // 256 KB
    float* CT   = (float*)(ws + (size_t)(144 << 20) + (256 << 10)); // 256 KB
    float* s32T = (float*)(ws + (size_t)(144 << 20) + (512 << 10)); // 16 KB
    float* dtT0 = (float*)Xi;     // b=0 half of dt (32 MB, Xi dead after conv)
    float* dtT1 = out;            // b=1 half of dt (d_out dead until final GEMM)

    // 1. w_in -> bf16
    f32_to_bf16_kernel<<<(2 * DINNER * DMODEL / 8) / 256, 256, 0, stream>>>(
        w_in, wb, 2 * DINNER * DMODEL / 8);
    // 2. RMSNorm
    rmsnorm_kernel<<<NTOK, 256, 0, stream>>>(x, norm_w, xn);
    // 3. in_proj GEMM (8-phase 256^2) -> split Xi / Zb (bf16)
    gemm8_split<<<dim3(NTOK / 256, 8192 / 256), 512, 0, stream>>>(
        xn, wb, Xi, Zb, DMODEL);
    // 4. fused conv + SiLU + transpose -> xc (row-major) and uT (into wb)
    conv_silu_t_kernel<<<dim3(LSEQ / 64, DINNER / 64, 2), 256, 0, stream>>>(
        Xi, conv_w, conv_b, xc, wb);
    // 5. x_proj -> BT/CT/s32T (transposed), 2 tokens/block
    xproj_kernel<<<NTOK / 2, 256, 0, stream>>>(xc, w_xp, BT, CT, s32T);
    // 5c. dt precompute (Xi dead after conv; out dead until step 8)
    dt_kernel<<<NCHAIN, 256, 0, stream>>>(s32T, dt_w, dt_b, dtT0, dtT1);
    // 6. selective scan, 2 chains/lane (gated y written into xc)
    scan_state_kernel<<<NCHAIN / 32, 256, 0, stream>>>(
        BT, CT, dtT0, dtT1, wb, Zb, xc, A_log, D_par);
    // 7. w_out -> bf16 into xn region
    f32_to_bf16_kernel<<<(DMODEL * DINNER / 8) / 256, 256, 0, stream>>>(
        w_out, xn, DMODEL * DINNER / 8);
    // 8. out_proj GEMM + residual -> fp32 out (overwrites dtT1 scratch)
    gemm_bt<true, true><<<dim3(NTOK / 128, DMODEL / 128), 256, 0, stream>>>(
        xc, xn, x, out, NTOK, DMODEL, DINNER);
}